// Round 1
// baseline (2416.014 us; speedup 1.0000x reference)
//
#include <hip/hip_runtime.h>
#include <hip/hip_bf16.h>

// Problem constants (fixed by the reference)
#define D_DIM 256
#define H_HEADS 8
#define L_LVLS 4
#define P_PTS 4
#define DFF 2048
#define DH 32
#define NQ 900
#define B_BATCH 8
#define S_TOT 12240
#define NROW (NQ * B_BATCH)   // 7200

// -------------------- elementwise add: c = a + b --------------------
__global__ __launch_bounds__(256) void add_kernel(
    const float* __restrict__ a, const float* __restrict__ b,
    float* __restrict__ c, int n) {
  int i = blockIdx.x * 256 + threadIdx.x;
  if (i < n) c[i] = a[i] + b[i];
}

// q_in[b,n,:] = q2[n,b,:] + qpe[n,b,:]   (transpose + add)
__global__ __launch_bounds__(256) void transadd_kernel(
    const float* __restrict__ a, const float* __restrict__ p,
    float* __restrict__ out) {
  int i = blockIdx.x * 256 + threadIdx.x;   // output flat index, (B,NQ,D)
  int d = i & 255;
  int orow = i >> 8;               // b*NQ + n
  int b = orow / NQ, n = orow % NQ;
  long irow = (long)n * B_BATCH + b;
  out[i] = a[irow * 256 + d] + p[irow * 256 + d];
}

// -------------------- generic SGEMM: C[M,N] = A[M,K] @ W[N,K]^T + bias --------------------
// AMODE 0: A row = r.  AMODE 1: output row r = b*Sdim+s reads A row s*Bdim+b.
#define BM 64
#define BN 64
#define BK 16
template<bool RELU, int AMODE>
__global__ __launch_bounds__(256) void gemm_bias(
    const float* __restrict__ A, const float* __restrict__ W,
    const float* __restrict__ bias, float* __restrict__ C,
    int M, int N, int K, int Sdim, int Bdim) {
  __shared__ float As[BK][BM + 4];
  __shared__ float Bs[BK][BN + 4];
  int tid = threadIdx.x;
  int tx = tid & 15, ty = tid >> 4;
  int m0 = blockIdx.y * BM, n0 = blockIdx.x * BN;
  int lk = tid & 15;       // k within K-tile
  int lrow = tid >> 4;     // 0..15
  float acc[4][4] = {};
  for (int k0 = 0; k0 < K; k0 += BK) {
    #pragma unroll
    for (int i = 0; i < 4; i++) {
      int m = m0 + lrow + 16 * i;
      float v = 0.f;
      if (m < M) {
        long arow = (AMODE == 0) ? (long)m : (long)(m % Sdim) * Bdim + (m / Sdim);
        v = A[arow * K + k0 + lk];
      }
      As[lk][lrow + 16 * i] = v;
    }
    #pragma unroll
    for (int i = 0; i < 4; i++) {
      int n = n0 + lrow + 16 * i;
      Bs[lk][lrow + 16 * i] = W[(long)n * K + k0 + lk];
    }
    __syncthreads();
    #pragma unroll
    for (int kk = 0; kk < BK; kk++) {
      float a[4], b[4];
      #pragma unroll
      for (int i = 0; i < 4; i++) a[i] = As[kk][ty * 4 + i];
      #pragma unroll
      for (int j = 0; j < 4; j++) b[j] = Bs[kk][tx * 4 + j];
      #pragma unroll
      for (int i = 0; i < 4; i++)
        #pragma unroll
        for (int j = 0; j < 4; j++) acc[i][j] += a[i] * b[j];
    }
    __syncthreads();
  }
  #pragma unroll
  for (int i = 0; i < 4; i++) {
    int m = m0 + ty * 4 + i;
    if (m >= M) continue;
    #pragma unroll
    for (int j = 0; j < 4; j++) {
      int n = n0 + tx * 4 + j;
      float v = acc[i][j] + bias[n];
      if (RELU) v = fmaxf(v, 0.f);
      C[(long)m * N + n] = v;
    }
  }
}

// -------------------- self-attention: one wave per (b,h,q-row) --------------------
// q,k,v in (NQ,B,D) layout; att out in (NQ,B,D).
__global__ __launch_bounds__(256) void attn_kernel(
    const float* __restrict__ q, const float* __restrict__ k,
    const float* __restrict__ v, float* __restrict__ att) {
  int wave = blockIdx.x * 4 + (threadIdx.x >> 6);
  int lane = threadIdx.x & 63;
  int b = wave / (H_HEADS * NQ);
  int r = wave % (H_HEADS * NQ);
  int h = r / NQ;
  int n = r % NQ;
  const float scale = 0.17677669529663687f;  // 1/sqrt(32)
  const float* qp = q + ((long)n * B_BATCH + b) * 256 + h * 32;
  float4 qv[8];
  #pragma unroll
  for (int i = 0; i < 8; i++) qv[i] = ((const float4*)qp)[i];
  float m = -1e30f, s = 0.f;
  float o[32];
  #pragma unroll
  for (int i = 0; i < 32; i++) o[i] = 0.f;
  for (int nk = lane; nk < NQ; nk += 64) {
    const float* kp = k + ((long)nk * B_BATCH + b) * 256 + h * 32;
    float4 kv[8];
    #pragma unroll
    for (int i = 0; i < 8; i++) kv[i] = ((const float4*)kp)[i];
    float dot = 0.f;
    #pragma unroll
    for (int i = 0; i < 8; i++)
      dot += qv[i].x * kv[i].x + qv[i].y * kv[i].y + qv[i].z * kv[i].z + qv[i].w * kv[i].w;
    float sc = dot * scale;
    float mn = fmaxf(m, sc);
    float corr = __expf(m - mn);
    float p = __expf(sc - mn);
    s = s * corr + p;
    const float* vp = v + ((long)nk * B_BATCH + b) * 256 + h * 32;
    float4 vv[8];
    #pragma unroll
    for (int i = 0; i < 8; i++) vv[i] = ((const float4*)vp)[i];
    #pragma unroll
    for (int i = 0; i < 8; i++) {
      o[4 * i + 0] = o[4 * i + 0] * corr + p * vv[i].x;
      o[4 * i + 1] = o[4 * i + 1] * corr + p * vv[i].y;
      o[4 * i + 2] = o[4 * i + 2] * corr + p * vv[i].z;
      o[4 * i + 3] = o[4 * i + 3] * corr + p * vv[i].w;
    }
    m = mn;
  }
  // cross-lane merge of per-lane online-softmax states
  float M = m;
  #pragma unroll
  for (int off = 32; off; off >>= 1) M = fmaxf(M, __shfl_xor(M, off));
  float f = __expf(m - M);
  s *= f;
  #pragma unroll
  for (int off = 32; off; off >>= 1) s += __shfl_xor(s, off);
  #pragma unroll
  for (int i = 0; i < 32; i++) {
    float val = o[i] * f;
    #pragma unroll
    for (int off = 32; off; off >>= 1) val += __shfl_xor(val, off);
    o[i] = val;
  }
  if (lane < 32) {
    float outv = 0.f;
    #pragma unroll
    for (int i = 0; i < 32; i++)
      if (lane == i) outv = o[i];
    att[((long)n * B_BATCH + b) * 256 + h * 32 + lane] = outv / s;
  }
}

// -------------------- residual + layernorm --------------------
// out[row,:] = LN(X[row,:] + R[rrow,:]) ; BMODE 1: row=(n*B+b) reads R row (b*NQ+n)
template<int BMODE>
__global__ __launch_bounds__(256) void resid_ln(
    const float* __restrict__ X, const float* __restrict__ R,
    const float* __restrict__ g, const float* __restrict__ be,
    float* __restrict__ out) {
  int row = blockIdx.x;
  int d = threadIdx.x;
  long rrow;
  if (BMODE == 0) rrow = row;
  else { int b = row % B_BATCH; int n = row / B_BATCH; rrow = (long)b * NQ + n; }
  float x = X[(long)row * 256 + d] + R[rrow * 256 + d];
  float s1 = x, s2 = x * x;
  #pragma unroll
  for (int off = 32; off; off >>= 1) {
    s1 += __shfl_xor(s1, off);
    s2 += __shfl_xor(s2, off);
  }
  __shared__ float a1[4], a2[4];
  int w = d >> 6, l = d & 63;
  if (l == 0) { a1[w] = s1; a2[w] = s2; }
  __syncthreads();
  float S1 = a1[0] + a1[1] + a1[2] + a1[3];
  float S2 = a2[0] + a2[1] + a2[2] + a2[3];
  float mean = S1 * (1.f / 256.f);
  float var = S2 * (1.f / 256.f) - mean * mean;
  out[(long)row * 256 + d] = (x - mean) * rsqrtf(var + 1e-5f) * g[d] + be[d];
}

// -------------------- deformable-attention sampling --------------------
// One block per (b,q); threads: h = tid/32, c = tid%32.
__global__ __launch_bounds__(256) void deform_sample(
    const float* __restrict__ value, const float* __restrict__ offs,
    const float* __restrict__ aw, const float* __restrict__ qrp,
    float* __restrict__ samp) {
  int bq = blockIdx.x;  // b*NQ + q
  int b = bq / NQ, q = bq % NQ;
  int h = threadIdx.x >> 5, c = threadIdx.x & 31;
  __shared__ float Wl[8][16], Lx[8][16], Ly[8][16];
  if (c < 16) {
    float a = aw[(long)bq * 128 + h * 16 + c];
    float ox = offs[(long)bq * 256 + (h * 16 + c) * 2 + 0];
    float oy = offs[(long)bq * 256 + (h * 16 + c) * 2 + 1];
    const float* rp = qrp + ((long)q * B_BATCH + b) * 4;
    Lx[h][c] = rp[0] + ox * 0.25f * rp[2] * 0.5f;
    Ly[h][c] = rp[1] + oy * 0.25f * rp[3] * 0.5f;
    Wl[h][c] = a;
  }
  __syncthreads();
  if (threadIdx.x < 8) {
    int hh = threadIdx.x;
    float mx = -1e30f;
    for (int i = 0; i < 16; i++) mx = fmaxf(mx, Wl[hh][i]);
    float sm = 0.f;
    for (int i = 0; i < 16; i++) { float e = __expf(Wl[hh][i] - mx); Wl[hh][i] = e; sm += e; }
    float inv = 1.f / sm;
    for (int i = 0; i < 16; i++) Wl[hh][i] *= inv;
  }
  __syncthreads();
  const int lvlW[4] = {96, 48, 24, 12};
  const int lvlS[4] = {0, 9216, 11520, 12096};
  float acc = 0.f;
  const float* vb = value + (long)b * S_TOT * 256 + h * 32 + c;
  #pragma unroll
  for (int l = 0; l < 4; l++) {
    int ww = lvlW[l], hh2 = lvlW[l], st = lvlS[l];
    #pragma unroll
    for (int p = 0; p < 4; p++) {
      int lp = l * 4 + p;
      float wgt = Wl[h][lp];
      float x = Lx[h][lp] * ww - 0.5f;
      float y = Ly[h][lp] * hh2 - 0.5f;
      float x0f = floorf(x), y0f = floorf(y);
      float lx = x - x0f, ly = y - y0f;
      int x0 = (int)x0f, y0 = (int)y0f;
      #pragma unroll
      for (int cy = 0; cy < 2; cy++) {
        #pragma unroll
        for (int cx = 0; cx < 2; cx++) {
          int xi = x0 + cx, yi = y0 + cy;
          float cw = (cx ? lx : 1.f - lx) * (cy ? ly : 1.f - ly);
          bool valid = (xi >= 0) && (xi < ww) && (yi >= 0) && (yi < hh2);
          int xc = min(max(xi, 0), ww - 1);
          int yc = min(max(yi, 0), hh2 - 1);
          float vv = vb[(long)(st + yc * ww + xc) * 256];
          acc += (valid ? cw * wgt : 0.f) * vv;
        }
      }
    }
  }
  samp[(long)bq * 256 + h * 32 + c] = acc;
}

// -------------------- host launch --------------------
extern "C" void kernel_launch(void* const* d_in, const int* in_sizes, int n_in,
                              void* d_out, int out_size, void* d_ws, size_t ws_size,
                              hipStream_t stream) {
  const float* queries = (const float*)d_in[0];
  const float* qpe     = (const float*)d_in[1];
  const float* qrp     = (const float*)d_in[2];
  const float* memory  = (const float*)d_in[3];
  const float* in_w    = (const float*)d_in[7];
  const float* in_b    = (const float*)d_in[8];
  const float* out_w   = (const float*)d_in[9];
  const float* out_b   = (const float*)d_in[10];
  const float* n1g = (const float*)d_in[11];
  const float* n1b = (const float*)d_in[12];
  const float* n2g = (const float*)d_in[13];
  const float* n2b = (const float*)d_in[14];
  const float* n3g = (const float*)d_in[15];
  const float* n3b = (const float*)d_in[16];
  const float* l1w = (const float*)d_in[17];
  const float* l1b = (const float*)d_in[18];
  const float* l2w = (const float*)d_in[19];
  const float* l2b = (const float*)d_in[20];
  const float* off_w = (const float*)d_in[21];
  const float* off_b = (const float*)d_in[22];
  const float* aw_w  = (const float*)d_in[23];
  const float* aw_b  = (const float*)d_in[24];
  const float* val_w = (const float*)d_in[25];
  const float* val_b = (const float*)d_in[26];
  const float* cout_w = (const float*)d_in[27];
  const float* cout_b = (const float*)d_in[28];

  float* ws = (float*)d_ws;
  const long E = (long)NROW * 256;  // 1,843,200
  float* qk    = ws + 0 * E;
  float* qbuf  = ws + 1 * E;
  float* kbuf  = ws + 2 * E;
  float* vbuf  = ws + 3 * E;
  float* att   = ws + 4 * E;
  float* sa    = ws + 5 * E;
  float* q2    = ws + 6 * E;
  float* value = ws + 7 * E;          // 25,067,520 floats
  // reuse after self-attn:
  float* q_in  = qbuf;
  float* offs  = kbuf;
  float* awb   = vbuf;
  float* samp  = qk;
  float* ca    = att;
  float* q3    = sa;
  float* hidden = value;              // value dead after sampling; 14.7M <= 25.1M
  float* ffn   = qbuf;

  dim3 blk(256);
  dim3 g7200(NROW);
  int mt = (NROW + BM - 1) / BM;      // 113

  // 1. qk = queries + qpe
  add_kernel<<<dim3((int)(E / 256)), blk, 0, stream>>>(queries, qpe, qk, (int)E);
  // 2-4. in-proj q,k,v
  gemm_bias<false, 0><<<dim3(4, mt), blk, 0, stream>>>(qk, in_w, in_b, qbuf, NROW, 256, 256, 0, 0);
  gemm_bias<false, 0><<<dim3(4, mt), blk, 0, stream>>>(qk, in_w + 65536, in_b + 256, kbuf, NROW, 256, 256, 0, 0);
  gemm_bias<false, 0><<<dim3(4, mt), blk, 0, stream>>>(queries, in_w + 131072, in_b + 512, vbuf, NROW, 256, 256, 0, 0);
  // 5. self-attention
  attn_kernel<<<dim3(B_BATCH * H_HEADS * NQ / 4), blk, 0, stream>>>(qbuf, kbuf, vbuf, att);
  // 6. out-proj
  gemm_bias<false, 0><<<dim3(4, mt), blk, 0, stream>>>(att, out_w, out_b, sa, NROW, 256, 256, 0, 0);
  // 7. q2 = LN(queries + sa) [norm2]
  resid_ln<0><<<g7200, blk, 0, stream>>>(queries, sa, n2g, n2b, q2);
  // 8. q_in = (q2 + qpe)^T  -> (B,NQ,D)
  transadd_kernel<<<dim3((int)(E / 256)), blk, 0, stream>>>(q2, qpe, q_in);
  // 9-10. offsets + attention-weight projections
  gemm_bias<false, 0><<<dim3(4, mt), blk, 0, stream>>>(q_in, off_w, off_b, offs, NROW, 256, 256, 0, 0);
  gemm_bias<false, 0><<<dim3(2, mt), blk, 0, stream>>>(q_in, aw_w, aw_b, awb, NROW, 128, 256, 0, 0);
  // 11. value projection (reads memory (S,B,D) into value (B,S,D))
  gemm_bias<false, 1><<<dim3(4, (B_BATCH * S_TOT) / BM), blk, 0, stream>>>(
      memory, val_w, val_b, value, B_BATCH * S_TOT, 256, 256, S_TOT, B_BATCH);
  // 12. deformable sampling
  deform_sample<<<g7200, blk, 0, stream>>>(value, offs, awb, qrp, samp);
  // 13. cross-attn output proj
  gemm_bias<false, 0><<<dim3(4, mt), blk, 0, stream>>>(samp, cout_w, cout_b, ca, NROW, 256, 256, 0, 0);
  // 14. q3 = LN(q2 + ca^T) [norm1]
  resid_ln<1><<<g7200, blk, 0, stream>>>(q2, ca, n1g, n1b, q3);
  // 15. FFN lin1 + relu
  gemm_bias<true, 0><<<dim3(32, mt), blk, 0, stream>>>(q3, l1w, l1b, hidden, NROW, DFF, 256, 0, 0);
  // 16. FFN lin2
  gemm_bias<false, 0><<<dim3(4, mt), blk, 0, stream>>>(hidden, l2w, l2b, ffn, NROW, 256, DFF, 0, 0);
  // 17. out = LN(q3 + ffn) [norm3]
  resid_ln<0><<<g7200, blk, 0, stream>>>(q3, ffn, n3g, n3b, (float*)d_out);
}

// Round 3
// 1178.619 us; speedup vs baseline: 2.0499x; 2.0499x over previous
//
#include <hip/hip_runtime.h>
#include <hip/hip_bf16.h>

// Problem constants (fixed by the reference)
#define D_DIM 256
#define H_HEADS 8
#define L_LVLS 4
#define P_PTS 4
#define DFF 2048
#define DH 32
#define NQ 900
#define B_BATCH 8
#define S_TOT 12240
#define NROW (NQ * B_BATCH)   // 7200

// -------------------- elementwise add: c = a + b --------------------
__global__ __launch_bounds__(256) void add_kernel(
    const float* __restrict__ a, const float* __restrict__ b,
    float* __restrict__ c, int n) {
  int i = blockIdx.x * 256 + threadIdx.x;
  if (i < n) c[i] = a[i] + b[i];
}

// q_in[b,n,:] = q2[n,b,:] + qpe[n,b,:]   (transpose + add)
__global__ __launch_bounds__(256) void transadd_kernel(
    const float* __restrict__ a, const float* __restrict__ p,
    float* __restrict__ out) {
  int i = blockIdx.x * 256 + threadIdx.x;   // output flat index, (B,NQ,D)
  int d = i & 255;
  int orow = i >> 8;               // b*NQ + n
  int b = orow / NQ, n = orow % NQ;
  long irow = (long)n * B_BATCH + b;
  out[i] = a[irow * 256 + d] + p[irow * 256 + d];
}

// -------------------- generic SGEMM: C[M,N] = A[M,K] @ W[N,K]^T + bias --------------------
// AMODE 0: A row = r.  AMODE 1: output row r = b*Sdim+s reads A row s*Bdim+b.
#define BM 64
#define BN 64
#define BK 16
template<bool RELU, int AMODE>
__global__ __launch_bounds__(256) void gemm_bias(
    const float* __restrict__ A, const float* __restrict__ W,
    const float* __restrict__ bias, float* __restrict__ C,
    int M, int N, int K, int Sdim, int Bdim) {
  __shared__ float As[BK][BM + 4];
  __shared__ float Bs[BK][BN + 4];
  int tid = threadIdx.x;
  int tx = tid & 15, ty = tid >> 4;
  int m0 = blockIdx.y * BM, n0 = blockIdx.x * BN;
  int lk = tid & 15;       // k within K-tile
  int lrow = tid >> 4;     // 0..15
  float acc[4][4] = {};
  for (int k0 = 0; k0 < K; k0 += BK) {
    #pragma unroll
    for (int i = 0; i < 4; i++) {
      int m = m0 + lrow + 16 * i;
      float v = 0.f;
      if (m < M) {
        long arow = (AMODE == 0) ? (long)m : (long)(m % Sdim) * Bdim + (m / Sdim);
        v = A[arow * K + k0 + lk];
      }
      As[lk][lrow + 16 * i] = v;
    }
    #pragma unroll
    for (int i = 0; i < 4; i++) {
      int n = n0 + lrow + 16 * i;
      Bs[lk][lrow + 16 * i] = W[(long)n * K + k0 + lk];
    }
    __syncthreads();
    #pragma unroll
    for (int kk = 0; kk < BK; kk++) {
      float a[4], b[4];
      #pragma unroll
      for (int i = 0; i < 4; i++) a[i] = As[kk][ty * 4 + i];
      #pragma unroll
      for (int j = 0; j < 4; j++) b[j] = Bs[kk][tx * 4 + j];
      #pragma unroll
      for (int i = 0; i < 4; i++)
        #pragma unroll
        for (int j = 0; j < 4; j++) acc[i][j] += a[i] * b[j];
    }
    __syncthreads();
  }
  #pragma unroll
  for (int i = 0; i < 4; i++) {
    int m = m0 + ty * 4 + i;
    if (m >= M) continue;
    #pragma unroll
    for (int j = 0; j < 4; j++) {
      int n = n0 + tx * 4 + j;
      float v = acc[i][j] + bias[n];
      if (RELU) v = fmaxf(v, 0.f);
      C[(long)m * N + n] = v;
    }
  }
}

// -------------------- self-attention v2: one thread per query, K/V tiles in LDS ------
// q,k,v in (NQ,B,D) layout; att out in (NQ,B,D).
// Block = (qtile of 225 queries, bh). 256 threads; K/V staged coalesced into LDS
// (each thread stages TWO float4 slots -> full 32-float rows), then broadcast
// ds_read_b128 per key row (conflict-free).
#define KT 64
#define QT 225
__global__ __launch_bounds__(256) void attn_kernel(
    const float* __restrict__ q, const float* __restrict__ k,
    const float* __restrict__ v, float* __restrict__ att) {
  int bh = blockIdx.y;            // b*8+h
  int b = bh >> 3, h = bh & 7;
  int qt = blockIdx.x;            // 0..3
  int tid = threadIdx.x;
  int myq = qt * QT + tid;
  bool act = tid < QT;
  __shared__ float Ks[KT][36];    // stride 36 floats: rows 144B (16B-aligned)
  __shared__ float Vs[KT][36];
  const float scale = 0.17677669529663687f;  // 1/sqrt(32)
  float4 qv[8];
  if (act) {
    const float* qp = q + ((long)myq * B_BATCH + b) * 256 + h * 32;
    #pragma unroll
    for (int i = 0; i < 8; i++) qv[i] = ((const float4*)qp)[i];
  }
  float m = -1e30f, l = 0.f;
  float o[32];
  #pragma unroll
  for (int i = 0; i < 32; i++) o[i] = 0.f;
  int sr = tid >> 2, sj = tid & 3;   // staging: row 0..63, float4 slots sj and sj+4
  for (int k0 = 0; k0 < NQ; k0 += KT) {
    int nk = k0 + sr;
    if (nk < NQ) {
      const float* kp = k + ((long)nk * B_BATCH + b) * 256 + h * 32;
      const float* vp = v + ((long)nk * B_BATCH + b) * 256 + h * 32;
      float4 ka = ((const float4*)kp)[sj];
      float4 kb = ((const float4*)kp)[sj + 4];
      float4 va = ((const float4*)vp)[sj];
      float4 vb4 = ((const float4*)vp)[sj + 4];
      *(float4*)&Ks[sr][sj * 4] = ka;
      *(float4*)&Ks[sr][sj * 4 + 16] = kb;
      *(float4*)&Vs[sr][sj * 4] = va;
      *(float4*)&Vs[sr][sj * 4 + 16] = vb4;
    }
    __syncthreads();
    int kn = min(KT, NQ - k0);
    if (act) {
      for (int kk = 0; kk < kn; kk++) {
        const float4* kr = (const float4*)&Ks[kk][0];
        float4 k4[8];
        #pragma unroll
        for (int i = 0; i < 8; i++) k4[i] = kr[i];
        float d0 = 0.f, d1 = 0.f, d2 = 0.f, d3 = 0.f;
        #pragma unroll
        for (int i = 0; i < 8; i += 4) {
          d0 += qv[i+0].x*k4[i+0].x + qv[i+0].y*k4[i+0].y + qv[i+0].z*k4[i+0].z + qv[i+0].w*k4[i+0].w;
          d1 += qv[i+1].x*k4[i+1].x + qv[i+1].y*k4[i+1].y + qv[i+1].z*k4[i+1].z + qv[i+1].w*k4[i+1].w;
          d2 += qv[i+2].x*k4[i+2].x + qv[i+2].y*k4[i+2].y + qv[i+2].z*k4[i+2].z + qv[i+2].w*k4[i+2].w;
          d3 += qv[i+3].x*k4[i+3].x + qv[i+3].y*k4[i+3].y + qv[i+3].z*k4[i+3].z + qv[i+3].w*k4[i+3].w;
        }
        float sc = ((d0 + d1) + (d2 + d3)) * scale;
        float mn = fmaxf(m, sc);
        float corr = __expf(m - mn);
        float p = __expf(sc - mn);
        l = l * corr + p;
        m = mn;
        const float4* vr = (const float4*)&Vs[kk][0];
        #pragma unroll
        for (int i = 0; i < 8; i++) {
          float4 v4 = vr[i];
          o[4*i+0] = o[4*i+0] * corr + p * v4.x;
          o[4*i+1] = o[4*i+1] * corr + p * v4.y;
          o[4*i+2] = o[4*i+2] * corr + p * v4.z;
          o[4*i+3] = o[4*i+3] * corr + p * v4.w;
        }
      }
    }
    __syncthreads();
  }
  if (act) {
    float inv = 1.f / l;
    float* op = att + ((long)myq * B_BATCH + b) * 256 + h * 32;
    #pragma unroll
    for (int i = 0; i < 8; i++) {
      float4 t4;
      t4.x = o[4*i+0] * inv; t4.y = o[4*i+1] * inv;
      t4.z = o[4*i+2] * inv; t4.w = o[4*i+3] * inv;
      ((float4*)op)[i] = t4;
    }
  }
}

// -------------------- residual + layernorm --------------------
// out[row,:] = LN(X[row,:] + R[rrow,:]) ; BMODE 1: row=(n*B+b) reads R row (b*NQ+n)
template<int BMODE>
__global__ __launch_bounds__(256) void resid_ln(
    const float* __restrict__ X, const float* __restrict__ R,
    const float* __restrict__ g, const float* __restrict__ be,
    float* __restrict__ out) {
  int row = blockIdx.x;
  int d = threadIdx.x;
  long rrow;
  if (BMODE == 0) rrow = row;
  else { int b = row % B_BATCH; int n = row / B_BATCH; rrow = (long)b * NQ + n; }
  float x = X[(long)row * 256 + d] + R[rrow * 256 + d];
  float s1 = x, s2 = x * x;
  #pragma unroll
  for (int off = 32; off; off >>= 1) {
    s1 += __shfl_xor(s1, off);
    s2 += __shfl_xor(s2, off);
  }
  __shared__ float a1[4], a2[4];
  int w = d >> 6, lidx = d & 63;
  if (lidx == 0) { a1[w] = s1; a2[w] = s2; }
  __syncthreads();
  float S1 = a1[0] + a1[1] + a1[2] + a1[3];
  float S2 = a2[0] + a2[1] + a2[2] + a2[3];
  float mean = S1 * (1.f / 256.f);
  float var = S2 * (1.f / 256.f) - mean * mean;
  out[(long)row * 256 + d] = (x - mean) * rsqrtf(var + 1e-5f) * g[d] + be[d];
}

// -------------------- deformable-attention sampling --------------------
// One block per (b,q); threads: h = tid/32, c = tid%32.
__global__ __launch_bounds__(256) void deform_sample(
    const float* __restrict__ value, const float* __restrict__ offs,
    const float* __restrict__ aw, const float* __restrict__ qrp,
    float* __restrict__ samp) {
  int bq = blockIdx.x;  // b*NQ + q
  int b = bq / NQ, q = bq % NQ;
  int h = threadIdx.x >> 5, c = threadIdx.x & 31;
  __shared__ float Wl[8][16], Lx[8][16], Ly[8][16];
  if (c < 16) {
    float a = aw[(long)bq * 128 + h * 16 + c];
    float ox = offs[(long)bq * 256 + (h * 16 + c) * 2 + 0];
    float oy = offs[(long)bq * 256 + (h * 16 + c) * 2 + 1];
    const float* rp = qrp + ((long)q * B_BATCH + b) * 4;
    Lx[h][c] = rp[0] + ox * 0.25f * rp[2] * 0.5f;
    Ly[h][c] = rp[1] + oy * 0.25f * rp[3] * 0.5f;
    Wl[h][c] = a;
  }
  __syncthreads();
  if (threadIdx.x < 8) {
    int hh = threadIdx.x;
    float mx = -1e30f;
    for (int i = 0; i < 16; i++) mx = fmaxf(mx, Wl[hh][i]);
    float sm = 0.f;
    for (int i = 0; i < 16; i++) { float e = __expf(Wl[hh][i] - mx); Wl[hh][i] = e; sm += e; }
    float inv = 1.f / sm;
    for (int i = 0; i < 16; i++) Wl[hh][i] *= inv;
  }
  __syncthreads();
  const int lvlW[4] = {96, 48, 24, 12};
  const int lvlS[4] = {0, 9216, 11520, 12096};
  float acc = 0.f;
  const float* vb = value + (long)b * S_TOT * 256 + h * 32 + c;
  #pragma unroll
  for (int l = 0; l < 4; l++) {
    int ww = lvlW[l], hh2 = lvlW[l], st = lvlS[l];
    #pragma unroll
    for (int p = 0; p < 4; p++) {
      int lp = l * 4 + p;
      float wgt = Wl[h][lp];
      float x = Lx[h][lp] * ww - 0.5f;
      float y = Ly[h][lp] * hh2 - 0.5f;
      float x0f = floorf(x), y0f = floorf(y);
      float lx = x - x0f, ly = y - y0f;
      int x0 = (int)x0f, y0 = (int)y0f;
      #pragma unroll
      for (int cy = 0; cy < 2; cy++) {
        #pragma unroll
        for (int cx = 0; cx < 2; cx++) {
          int xi = x0 + cx, yi = y0 + cy;
          float cw = (cx ? lx : 1.f - lx) * (cy ? ly : 1.f - ly);
          bool valid = (xi >= 0) && (xi < ww) && (yi >= 0) && (yi < hh2);
          int xc = min(max(xi, 0), ww - 1);
          int yc = min(max(yi, 0), hh2 - 1);
          float vv = vb[(long)(st + yc * ww + xc) * 256];
          acc += (valid ? cw * wgt : 0.f) * vv;
        }
      }
    }
  }
  samp[(long)bq * 256 + h * 32 + c] = acc;
}

// -------------------- host launch --------------------
extern "C" void kernel_launch(void* const* d_in, const int* in_sizes, int n_in,
                              void* d_out, int out_size, void* d_ws, size_t ws_size,
                              hipStream_t stream) {
  const float* queries = (const float*)d_in[0];
  const float* qpe     = (const float*)d_in[1];
  const float* qrp     = (const float*)d_in[2];
  const float* memory  = (const float*)d_in[3];
  const float* in_w    = (const float*)d_in[7];
  const float* in_b    = (const float*)d_in[8];
  const float* out_w   = (const float*)d_in[9];
  const float* out_b   = (const float*)d_in[10];
  const float* n1g = (const float*)d_in[11];
  const float* n1b = (const float*)d_in[12];
  const float* n2g = (const float*)d_in[13];
  const float* n2b = (const float*)d_in[14];
  const float* n3g = (const float*)d_in[15];
  const float* n3b = (const float*)d_in[16];
  const float* l1w = (const float*)d_in[17];
  const float* l1b = (const float*)d_in[18];
  const float* l2w = (const float*)d_in[19];
  const float* l2b = (const float*)d_in[20];
  const float* off_w = (const float*)d_in[21];
  const float* off_b = (const float*)d_in[22];
  const float* aw_w  = (const float*)d_in[23];
  const float* aw_b  = (const float*)d_in[24];
  const float* val_w = (const float*)d_in[25];
  const float* val_b = (const float*)d_in[26];
  const float* cout_w = (const float*)d_in[27];
  const float* cout_b = (const float*)d_in[28];

  float* ws = (float*)d_ws;
  const long E = (long)NROW * 256;  // 1,843,200
  float* qk    = ws + 0 * E;
  float* qbuf  = ws + 1 * E;
  float* kbuf  = ws + 2 * E;
  float* vbuf  = ws + 3 * E;
  float* att   = ws + 4 * E;
  float* sa    = ws + 5 * E;
  float* q2    = ws + 6 * E;
  float* value = ws + 7 * E;          // 25,067,520 floats
  // reuse after self-attn:
  float* q_in  = qbuf;
  float* offs  = kbuf;
  float* awb   = vbuf;
  float* samp  = qk;
  float* ca    = att;
  float* q3    = sa;
  float* hidden = value;              // value dead after sampling; 14.7M <= 25.1M
  float* ffn   = qbuf;

  dim3 blk(256);
  dim3 g7200(NROW);
  int mt = (NROW + BM - 1) / BM;      // 113

  // 1. qk = queries + qpe
  add_kernel<<<dim3((int)(E / 256)), blk, 0, stream>>>(queries, qpe, qk, (int)E);
  // 2-4. in-proj q,k,v
  gemm_bias<false, 0><<<dim3(4, mt), blk, 0, stream>>>(qk, in_w, in_b, qbuf, NROW, 256, 256, 0, 0);
  gemm_bias<false, 0><<<dim3(4, mt), blk, 0, stream>>>(qk, in_w + 65536, in_b + 256, kbuf, NROW, 256, 256, 0, 0);
  gemm_bias<false, 0><<<dim3(4, mt), blk, 0, stream>>>(queries, in_w + 131072, in_b + 512, vbuf, NROW, 256, 256, 0, 0);
  // 5. self-attention (4 q-tiles of 225 x 64 bh)
  attn_kernel<<<dim3(4, B_BATCH * H_HEADS), blk, 0, stream>>>(qbuf, kbuf, vbuf, att);
  // 6. out-proj
  gemm_bias<false, 0><<<dim3(4, mt), blk, 0, stream>>>(att, out_w, out_b, sa, NROW, 256, 256, 0, 0);
  // 7. q2 = LN(queries + sa) [norm2]
  resid_ln<0><<<g7200, blk, 0, stream>>>(queries, sa, n2g, n2b, q2);
  // 8. q_in = (q2 + qpe)^T  -> (B,NQ,D)
  transadd_kernel<<<dim3((int)(E / 256)), blk, 0, stream>>>(q2, qpe, q_in);
  // 9-10. offsets + attention-weight projections
  gemm_bias<false, 0><<<dim3(4, mt), blk, 0, stream>>>(q_in, off_w, off_b, offs, NROW, 256, 256, 0, 0);
  gemm_bias<false, 0><<<dim3(2, mt), blk, 0, stream>>>(q_in, aw_w, aw_b, awb, NROW, 128, 256, 0, 0);
  // 11. value projection (reads memory (S,B,D) into value (B,S,D))
  gemm_bias<false, 1><<<dim3(4, (B_BATCH * S_TOT) / BM), blk, 0, stream>>>(
      memory, val_w, val_b, value, B_BATCH * S_TOT, 256, 256, S_TOT, B_BATCH);
  // 12. deformable sampling
  deform_sample<<<g7200, blk, 0, stream>>>(value, offs, awb, qrp, samp);
  // 13. cross-attn output proj
  gemm_bias<false, 0><<<dim3(4, mt), blk, 0, stream>>>(samp, cout_w, cout_b, ca, NROW, 256, 256, 0, 0);
  // 14. q3 = LN(q2 + ca^T) [norm1]
  resid_ln<1><<<g7200, blk, 0, stream>>>(q2, ca, n1g, n1b, q3);
  // 15. FFN lin1 + relu
  gemm_bias<true, 0><<<dim3(32, mt), blk, 0, stream>>>(q3, l1w, l1b, hidden, NROW, DFF, 256, 0, 0);
  // 16. FFN lin2
  gemm_bias<false, 0><<<dim3(4, mt), blk, 0, stream>>>(hidden, l2w, l2b, ffn, NROW, 256, DFF, 0, 0);
  // 17. out = LN(q3 + ffn) [norm3]
  resid_ln<0><<<g7200, blk, 0, stream>>>(q3, ffn, n3g, n3b, (float*)d_out);
}

// Round 4
// 796.977 us; speedup vs baseline: 3.0315x; 1.4789x over previous
//
#include <hip/hip_runtime.h>
#include <hip/hip_bf16.h>

// Problem constants (fixed by the reference)
#define D_DIM 256
#define H_HEADS 8
#define L_LVLS 4
#define P_PTS 4
#define DFF 2048
#define DH 32
#define NQ 900
#define B_BATCH 8
#define S_TOT 12240
#define NROW (NQ * B_BATCH)   // 7200

typedef __attribute__((ext_vector_type(8))) short short8;
typedef __attribute__((ext_vector_type(4))) float f32x4;

// float -> bf16 round-to-nearest-even (inputs finite)
__device__ __forceinline__ short f2bf(float x) {
  union { float f; unsigned u; } v; v.f = x;
  unsigned r = v.u + 0x7fff + ((v.u >> 16) & 1);
  return (short)(r >> 16);
}

// -------------------- elementwise add: c = a + b --------------------
__global__ __launch_bounds__(256) void add_kernel(
    const float* __restrict__ a, const float* __restrict__ b,
    float* __restrict__ c, int n) {
  int i = blockIdx.x * 256 + threadIdx.x;
  if (i < n) c[i] = a[i] + b[i];
}

// q_in[b,n,:] = q2[n,b,:] + qpe[n,b,:]   (transpose + add)
__global__ __launch_bounds__(256) void transadd_kernel(
    const float* __restrict__ a, const float* __restrict__ p,
    float* __restrict__ out) {
  int i = blockIdx.x * 256 + threadIdx.x;   // output flat index, (B,NQ,D)
  int d = i & 255;
  int orow = i >> 8;               // b*NQ + n
  int b = orow / NQ, n = orow % NQ;
  long irow = (long)n * B_BATCH + b;
  out[i] = a[irow * 256 + d] + p[irow * 256 + d];
}

// ---------------- MFMA GEMM: C[M,N] = A[M,K] @ W[N,K]^T + bias ----------------
// bf16 inputs via fused fp32->bf16 conversion in LDS staging; fp32 accumulate.
// Block tile 128x128, 4 waves in 2x2 grid each computing 64x64 via 4x4 frags of
// v_mfma_f32_16x16x32_bf16. BK=32. LDS row stride 40 bf16 (80B: 2-way alias only).
// AMODE 0: A row = m.  AMODE 1: m = b*Sdim+s reads A row s*Bdim+b.
// Requires: N % 128 == 0, K % 32 == 0.
#define GBM 128
#define GBK 32
#define LDA 40
template<bool RELU, int AMODE>
__global__ __launch_bounds__(256) void gemm_mfma(
    const float* __restrict__ A, const float* __restrict__ W,
    const float* __restrict__ bias, float* __restrict__ C,
    int M, int N, int K, int Sdim, int Bdim) {
  __shared__ short As[GBM * LDA];
  __shared__ short Bs[GBM * LDA];
  int tid = threadIdx.x;
  int wave = tid >> 6, lane = tid & 63;
  int wm = wave >> 1, wn = wave & 1;
  int quad = lane >> 4, l16 = lane & 15;
  int m0 = blockIdx.y * GBM, n0 = blockIdx.x * GBM;
  int srow = tid >> 1, shalf = tid & 1;   // staging: row 0..127, k-half 0/16

  // A source row (hoisted out of k-loop)
  int am = m0 + srow;
  bool avalid = am < M;
  long arow;
  if (AMODE == 0) arow = am;
  else arow = (long)(am % Sdim) * Bdim + (am / Sdim);
  const float* asrc = A + arow * (long)K + shalf * 16;
  const float* bsrc = W + (long)(n0 + srow) * K + shalf * 16;
  short* adst = &As[srow * LDA + shalf * 16];
  short* bdst = &Bs[srow * LDA + shalf * 16];

  f32x4 acc[4][4] = {};
  for (int k0 = 0; k0 < K; k0 += GBK) {
    short8 ta0 = {}, ta1 = {}, tb0, tb1;
    if (avalid) {
      float4 f0 = ((const float4*)(asrc + k0))[0];
      float4 f1 = ((const float4*)(asrc + k0))[1];
      float4 f2 = ((const float4*)(asrc + k0))[2];
      float4 f3 = ((const float4*)(asrc + k0))[3];
      ta0[0]=f2bf(f0.x); ta0[1]=f2bf(f0.y); ta0[2]=f2bf(f0.z); ta0[3]=f2bf(f0.w);
      ta0[4]=f2bf(f1.x); ta0[5]=f2bf(f1.y); ta0[6]=f2bf(f1.z); ta0[7]=f2bf(f1.w);
      ta1[0]=f2bf(f2.x); ta1[1]=f2bf(f2.y); ta1[2]=f2bf(f2.z); ta1[3]=f2bf(f2.w);
      ta1[4]=f2bf(f3.x); ta1[5]=f2bf(f3.y); ta1[6]=f2bf(f3.z); ta1[7]=f2bf(f3.w);
    }
    {
      float4 f0 = ((const float4*)(bsrc + k0))[0];
      float4 f1 = ((const float4*)(bsrc + k0))[1];
      float4 f2 = ((const float4*)(bsrc + k0))[2];
      float4 f3 = ((const float4*)(bsrc + k0))[3];
      tb0[0]=f2bf(f0.x); tb0[1]=f2bf(f0.y); tb0[2]=f2bf(f0.z); tb0[3]=f2bf(f0.w);
      tb0[4]=f2bf(f1.x); tb0[5]=f2bf(f1.y); tb0[6]=f2bf(f1.z); tb0[7]=f2bf(f1.w);
      tb1[0]=f2bf(f2.x); tb1[1]=f2bf(f2.y); tb1[2]=f2bf(f2.z); tb1[3]=f2bf(f2.w);
      tb1[4]=f2bf(f3.x); tb1[5]=f2bf(f3.y); tb1[6]=f2bf(f3.z); tb1[7]=f2bf(f3.w);
    }
    __syncthreads();   // protect LDS from previous iteration's readers
    *(short8*)adst = ta0;
    *(short8*)(adst + 8) = ta1;
    *(short8*)bdst = tb0;
    *(short8*)(bdst + 8) = tb1;
    __syncthreads();
    short8 af[4], bf[4];
    #pragma unroll
    for (int i = 0; i < 4; i++) {
      af[i] = *(const short8*)&As[(wm * 64 + i * 16 + l16) * LDA + quad * 8];
      bf[i] = *(const short8*)&Bs[(wn * 64 + i * 16 + l16) * LDA + quad * 8];
    }
    #pragma unroll
    for (int i = 0; i < 4; i++)
      #pragma unroll
      for (int j = 0; j < 4; j++)
        acc[i][j] = __builtin_amdgcn_mfma_f32_16x16x32_bf16(af[i], bf[j], acc[i][j], 0, 0, 0);
  }
  // epilogue: C[m][n] = acc + bias[n] (+ReLU). D: row=quad*4+reg, col=l16.
  #pragma unroll
  for (int i = 0; i < 4; i++) {
    int mbase = m0 + wm * 64 + i * 16 + quad * 4;
    #pragma unroll
    for (int r = 0; r < 4; r++) {
      int m = mbase + r;
      if (m < M) {
        #pragma unroll
        for (int j = 0; j < 4; j++) {
          int n = n0 + wn * 64 + j * 16 + l16;
          float v = acc[i][j][r] + bias[n];
          if (RELU) v = fmaxf(v, 0.f);
          C[(long)m * N + n] = v;
        }
      }
    }
  }
}

// -------------------- self-attention: one thread per query, K/V tiles in LDS ------
#define KT 64
#define QT 225
__global__ __launch_bounds__(256) void attn_kernel(
    const float* __restrict__ q, const float* __restrict__ k,
    const float* __restrict__ v, float* __restrict__ att) {
  int bh = blockIdx.y;            // b*8+h
  int b = bh >> 3, h = bh & 7;
  int qt = blockIdx.x;            // 0..3
  int tid = threadIdx.x;
  int myq = qt * QT + tid;
  bool act = tid < QT;
  __shared__ float Ks[KT][36];
  __shared__ float Vs[KT][36];
  const float scale = 0.17677669529663687f;  // 1/sqrt(32)
  float4 qv[8];
  if (act) {
    const float* qp = q + ((long)myq * B_BATCH + b) * 256 + h * 32;
    #pragma unroll
    for (int i = 0; i < 8; i++) qv[i] = ((const float4*)qp)[i];
  }
  float m = -1e30f, l = 0.f;
  float o[32];
  #pragma unroll
  for (int i = 0; i < 32; i++) o[i] = 0.f;
  int sr = tid >> 2, sj = tid & 3;
  for (int k0 = 0; k0 < NQ; k0 += KT) {
    int nk = k0 + sr;
    if (nk < NQ) {
      const float* kp = k + ((long)nk * B_BATCH + b) * 256 + h * 32;
      const float* vp = v + ((long)nk * B_BATCH + b) * 256 + h * 32;
      float4 ka = ((const float4*)kp)[sj];
      float4 kb = ((const float4*)kp)[sj + 4];
      float4 va = ((const float4*)vp)[sj];
      float4 vb4 = ((const float4*)vp)[sj + 4];
      *(float4*)&Ks[sr][sj * 4] = ka;
      *(float4*)&Ks[sr][sj * 4 + 16] = kb;
      *(float4*)&Vs[sr][sj * 4] = va;
      *(float4*)&Vs[sr][sj * 4 + 16] = vb4;
    }
    __syncthreads();
    int kn = min(KT, NQ - k0);
    if (act) {
      for (int kk = 0; kk < kn; kk++) {
        const float4* kr = (const float4*)&Ks[kk][0];
        float4 k4[8];
        #pragma unroll
        for (int i = 0; i < 8; i++) k4[i] = kr[i];
        float d0 = 0.f, d1 = 0.f, d2 = 0.f, d3 = 0.f;
        #pragma unroll
        for (int i = 0; i < 8; i += 4) {
          d0 += qv[i+0].x*k4[i+0].x + qv[i+0].y*k4[i+0].y + qv[i+0].z*k4[i+0].z + qv[i+0].w*k4[i+0].w;
          d1 += qv[i+1].x*k4[i+1].x + qv[i+1].y*k4[i+1].y + qv[i+1].z*k4[i+1].z + qv[i+1].w*k4[i+1].w;
          d2 += qv[i+2].x*k4[i+2].x + qv[i+2].y*k4[i+2].y + qv[i+2].z*k4[i+2].z + qv[i+2].w*k4[i+2].w;
          d3 += qv[i+3].x*k4[i+3].x + qv[i+3].y*k4[i+3].y + qv[i+3].z*k4[i+3].z + qv[i+3].w*k4[i+3].w;
        }
        float sc = ((d0 + d1) + (d2 + d3)) * scale;
        float mn = fmaxf(m, sc);
        float corr = __expf(m - mn);
        float p = __expf(sc - mn);
        l = l * corr + p;
        m = mn;
        const float4* vr = (const float4*)&Vs[kk][0];
        #pragma unroll
        for (int i = 0; i < 8; i++) {
          float4 v4 = vr[i];
          o[4*i+0] = o[4*i+0] * corr + p * v4.x;
          o[4*i+1] = o[4*i+1] * corr + p * v4.y;
          o[4*i+2] = o[4*i+2] * corr + p * v4.z;
          o[4*i+3] = o[4*i+3] * corr + p * v4.w;
        }
      }
    }
    __syncthreads();
  }
  if (act) {
    float inv = 1.f / l;
    float* op = att + ((long)myq * B_BATCH + b) * 256 + h * 32;
    #pragma unroll
    for (int i = 0; i < 8; i++) {
      float4 t4;
      t4.x = o[4*i+0] * inv; t4.y = o[4*i+1] * inv;
      t4.z = o[4*i+2] * inv; t4.w = o[4*i+3] * inv;
      ((float4*)op)[i] = t4;
    }
  }
}

// -------------------- residual + layernorm --------------------
template<int BMODE>
__global__ __launch_bounds__(256) void resid_ln(
    const float* __restrict__ X, const float* __restrict__ R,
    const float* __restrict__ g, const float* __restrict__ be,
    float* __restrict__ out) {
  int row = blockIdx.x;
  int d = threadIdx.x;
  long rrow;
  if (BMODE == 0) rrow = row;
  else { int b = row % B_BATCH; int n = row / B_BATCH; rrow = (long)b * NQ + n; }
  float x = X[(long)row * 256 + d] + R[rrow * 256 + d];
  float s1 = x, s2 = x * x;
  #pragma unroll
  for (int off = 32; off; off >>= 1) {
    s1 += __shfl_xor(s1, off);
    s2 += __shfl_xor(s2, off);
  }
  __shared__ float a1[4], a2[4];
  int w = d >> 6, lidx = d & 63;
  if (lidx == 0) { a1[w] = s1; a2[w] = s2; }
  __syncthreads();
  float S1 = a1[0] + a1[1] + a1[2] + a1[3];
  float S2 = a2[0] + a2[1] + a2[2] + a2[3];
  float mean = S1 * (1.f / 256.f);
  float var = S2 * (1.f / 256.f) - mean * mean;
  out[(long)row * 256 + d] = (x - mean) * rsqrtf(var + 1e-5f) * g[d] + be[d];
}

// -------------------- deformable-attention sampling --------------------
__global__ __launch_bounds__(256) void deform_sample(
    const float* __restrict__ value, const float* __restrict__ offs,
    const float* __restrict__ aw, const float* __restrict__ qrp,
    float* __restrict__ samp) {
  int bq = blockIdx.x;  // b*NQ + q
  int b = bq / NQ, q = bq % NQ;
  int h = threadIdx.x >> 5, c = threadIdx.x & 31;
  __shared__ float Wl[8][16], Lx[8][16], Ly[8][16];
  if (c < 16) {
    float a = aw[(long)bq * 128 + h * 16 + c];
    float ox = offs[(long)bq * 256 + (h * 16 + c) * 2 + 0];
    float oy = offs[(long)bq * 256 + (h * 16 + c) * 2 + 1];
    const float* rp = qrp + ((long)q * B_BATCH + b) * 4;
    Lx[h][c] = rp[0] + ox * 0.25f * rp[2] * 0.5f;
    Ly[h][c] = rp[1] + oy * 0.25f * rp[3] * 0.5f;
    Wl[h][c] = a;
  }
  __syncthreads();
  if (threadIdx.x < 8) {
    int hh = threadIdx.x;
    float mx = -1e30f;
    for (int i = 0; i < 16; i++) mx = fmaxf(mx, Wl[hh][i]);
    float sm = 0.f;
    for (int i = 0; i < 16; i++) { float e = __expf(Wl[hh][i] - mx); Wl[hh][i] = e; sm += e; }
    float inv = 1.f / sm;
    for (int i = 0; i < 16; i++) Wl[hh][i] *= inv;
  }
  __syncthreads();
  const int lvlW[4] = {96, 48, 24, 12};
  const int lvlS[4] = {0, 9216, 11520, 12096};
  float acc = 0.f;
  const float* vb = value + (long)b * S_TOT * 256 + h * 32 + c;
  #pragma unroll
  for (int l = 0; l < 4; l++) {
    int ww = lvlW[l], hh2 = lvlW[l], st = lvlS[l];
    #pragma unroll
    for (int p = 0; p < 4; p++) {
      int lp = l * 4 + p;
      float wgt = Wl[h][lp];
      float x = Lx[h][lp] * ww - 0.5f;
      float y = Ly[h][lp] * hh2 - 0.5f;
      float x0f = floorf(x), y0f = floorf(y);
      float lx = x - x0f, ly = y - y0f;
      int x0 = (int)x0f, y0 = (int)y0f;
      #pragma unroll
      for (int cy = 0; cy < 2; cy++) {
        #pragma unroll
        for (int cx = 0; cx < 2; cx++) {
          int xi = x0 + cx, yi = y0 + cy;
          float cw = (cx ? lx : 1.f - lx) * (cy ? ly : 1.f - ly);
          bool valid = (xi >= 0) && (xi < ww) && (yi >= 0) && (yi < hh2);
          int xc = min(max(xi, 0), ww - 1);
          int yc = min(max(yi, 0), hh2 - 1);
          float vv = vb[(long)(st + yc * ww + xc) * 256];
          acc += (valid ? cw * wgt : 0.f) * vv;
        }
      }
    }
  }
  samp[(long)bq * 256 + h * 32 + c] = acc;
}

// -------------------- host launch --------------------
extern "C" void kernel_launch(void* const* d_in, const int* in_sizes, int n_in,
                              void* d_out, int out_size, void* d_ws, size_t ws_size,
                              hipStream_t stream) {
  const float* queries = (const float*)d_in[0];
  const float* qpe     = (const float*)d_in[1];
  const float* qrp     = (const float*)d_in[2];
  const float* memory  = (const float*)d_in[3];
  const float* in_w    = (const float*)d_in[7];
  const float* in_b    = (const float*)d_in[8];
  const float* out_w   = (const float*)d_in[9];
  const float* out_b   = (const float*)d_in[10];
  const float* n1g = (const float*)d_in[11];
  const float* n1b = (const float*)d_in[12];
  const float* n2g = (const float*)d_in[13];
  const float* n2b = (const float*)d_in[14];
  const float* n3g = (const float*)d_in[15];
  const float* n3b = (const float*)d_in[16];
  const float* l1w = (const float*)d_in[17];
  const float* l1b = (const float*)d_in[18];
  const float* l2w = (const float*)d_in[19];
  const float* l2b = (const float*)d_in[20];
  const float* off_w = (const float*)d_in[21];
  const float* off_b = (const float*)d_in[22];
  const float* aw_w  = (const float*)d_in[23];
  const float* aw_b  = (const float*)d_in[24];
  const float* val_w = (const float*)d_in[25];
  const float* val_b = (const float*)d_in[26];
  const float* cout_w = (const float*)d_in[27];
  const float* cout_b = (const float*)d_in[28];

  float* ws = (float*)d_ws;
  const long E = (long)NROW * 256;  // 1,843,200
  float* qk    = ws + 0 * E;
  float* qbuf  = ws + 1 * E;
  float* kbuf  = ws + 2 * E;
  float* vbuf  = ws + 3 * E;
  float* att   = ws + 4 * E;
  float* sa    = ws + 5 * E;
  float* q2    = ws + 6 * E;
  float* value = ws + 7 * E;          // 25,067,520 floats
  // reuse after self-attn:
  float* q_in  = qbuf;
  float* offs  = kbuf;
  float* awb   = vbuf;
  float* samp  = qk;
  float* ca    = att;
  float* q3    = sa;
  float* hidden = value;              // value dead after sampling; 14.7M <= 25.1M
  float* ffn   = qbuf;

  dim3 blk(256);
  dim3 g7200(NROW);
  int mt = (NROW + GBM - 1) / GBM;    // 57

  // 1. qk = queries + qpe
  add_kernel<<<dim3((int)(E / 256)), blk, 0, stream>>>(queries, qpe, qk, (int)E);
  // 2-4. in-proj q,k,v
  gemm_mfma<false, 0><<<dim3(2, mt), blk, 0, stream>>>(qk, in_w, in_b, qbuf, NROW, 256, 256, 0, 0);
  gemm_mfma<false, 0><<<dim3(2, mt), blk, 0, stream>>>(qk, in_w + 65536, in_b + 256, kbuf, NROW, 256, 256, 0, 0);
  gemm_mfma<false, 0><<<dim3(2, mt), blk, 0, stream>>>(queries, in_w + 131072, in_b + 512, vbuf, NROW, 256, 256, 0, 0);
  // 5. self-attention (4 q-tiles of 225 x 64 bh)
  attn_kernel<<<dim3(4, B_BATCH * H_HEADS), blk, 0, stream>>>(qbuf, kbuf, vbuf, att);
  // 6. out-proj
  gemm_mfma<false, 0><<<dim3(2, mt), blk, 0, stream>>>(att, out_w, out_b, sa, NROW, 256, 256, 0, 0);
  // 7. q2 = LN(queries + sa) [norm2]
  resid_ln<0><<<g7200, blk, 0, stream>>>(queries, sa, n2g, n2b, q2);
  // 8. q_in = (q2 + qpe)^T  -> (B,NQ,D)
  transadd_kernel<<<dim3((int)(E / 256)), blk, 0, stream>>>(q2, qpe, q_in);
  // 9-10. offsets + attention-weight projections
  gemm_mfma<false, 0><<<dim3(2, mt), blk, 0, stream>>>(q_in, off_w, off_b, offs, NROW, 256, 256, 0, 0);
  gemm_mfma<false, 0><<<dim3(1, mt), blk, 0, stream>>>(q_in, aw_w, aw_b, awb, NROW, 128, 256, 0, 0);
  // 11. value projection (reads memory (S,B,D) into value (B,S,D))
  gemm_mfma<false, 1><<<dim3(2, (B_BATCH * S_TOT) / GBM), blk, 0, stream>>>(
      memory, val_w, val_b, value, B_BATCH * S_TOT, 256, 256, S_TOT, B_BATCH);
  // 12. deformable sampling
  deform_sample<<<g7200, blk, 0, stream>>>(value, offs, awb, qrp, samp);
  // 13. cross-attn output proj
  gemm_mfma<false, 0><<<dim3(2, mt), blk, 0, stream>>>(samp, cout_w, cout_b, ca, NROW, 256, 256, 0, 0);
  // 14. q3 = LN(q2 + ca^T) [norm1]
  resid_ln<1><<<g7200, blk, 0, stream>>>(q2, ca, n1g, n1b, q3);
  // 15. FFN lin1 + relu
  gemm_mfma<true, 0><<<dim3(16, mt), blk, 0, stream>>>(q3, l1w, l1b, hidden, NROW, DFF, 256, 0, 0);
  // 16. FFN lin2
  gemm_mfma<false, 0><<<dim3(2, mt), blk, 0, stream>>>(hidden, l2w, l2b, ffn, NROW, 256, DFF, 0, 0);
  // 17. out = LN(q3 + ffn) [norm3]
  resid_ln<0><<<g7200, blk, 0, stream>>>(q3, ffn, n3g, n3b, (float*)d_out);
}

// Round 5
// 663.015 us; speedup vs baseline: 3.6440x; 1.2020x over previous
//
#include <hip/hip_runtime.h>
#include <hip/hip_bf16.h>

// Problem constants (fixed by the reference)
#define D_DIM 256
#define H_HEADS 8
#define L_LVLS 4
#define P_PTS 4
#define DFF 2048
#define DH 32
#define NQ 900
#define B_BATCH 8
#define S_TOT 12240
#define NROW (NQ * B_BATCH)   // 7200

typedef __attribute__((ext_vector_type(8))) short short8;
typedef __attribute__((ext_vector_type(4))) short short4v;
typedef __attribute__((ext_vector_type(4))) float f32x4;

// float -> bf16 round-to-nearest-even (inputs finite)
__device__ __forceinline__ short f2bf(float x) {
  union { float f; unsigned u; } v; v.f = x;
  unsigned r = v.u + 0x7fff + ((v.u >> 16) & 1);
  return (short)(r >> 16);
}
__device__ __forceinline__ float bf2f(unsigned short u) {
  union { unsigned u; float f; } v; v.u = ((unsigned)u) << 16; return v.f;
}

// -------------------- fused weight conversion fp32->bf16 (8 segments) --------------------
struct WConvArgs {
  const float* src[8];
  short* dst[8];
  int end[8];
  int total;
};
__global__ __launch_bounds__(256) void wconv_kernel(WConvArgs a) {
  int i = blockIdx.x * 256 + threadIdx.x;
  if (i >= a.total) return;
  int seg = 0;
  while (seg < 7 && i >= a.end[seg]) seg++;
  int base = seg ? a.end[seg - 1] : 0;
  a.dst[seg][i - base] = f2bf(a.src[seg][i - base]);
}

// -------------------- c_bf = bf16(a + b), vectorized x4 --------------------
__global__ __launch_bounds__(256) void addbf_kernel(
    const float* __restrict__ a, const float* __restrict__ b, short* __restrict__ c) {
  int t = blockIdx.x * 256 + threadIdx.x;   // E/4 threads
  float4 x = ((const float4*)a)[t];
  float4 y = ((const float4*)b)[t];
  short4v o;
  o.x = f2bf(x.x + y.x); o.y = f2bf(x.y + y.y);
  o.z = f2bf(x.z + y.z); o.w = f2bf(x.w + y.w);
  ((short4v*)c)[t] = o;
}

// -------------------- d_bf = bf16(s), vectorized x4 --------------------
__global__ __launch_bounds__(256) void conv_kernel(
    const float* __restrict__ s, short* __restrict__ d) {
  int t = blockIdx.x * 256 + threadIdx.x;
  float4 x = ((const float4*)s)[t];
  short4v o;
  o.x = f2bf(x.x); o.y = f2bf(x.y); o.z = f2bf(x.z); o.w = f2bf(x.w);
  ((short4v*)d)[t] = o;
}

// qin_bf[b,n,:] = bf16(q2[n,b,:] + qpe[n,b,:])   (transpose + add)
__global__ __launch_bounds__(256) void transaddbf_kernel(
    const float* __restrict__ a, const float* __restrict__ p, short* __restrict__ out) {
  int t = blockIdx.x * 256 + threadIdx.x;   // E/4
  int d4 = t & 63;
  int orow = t >> 6;               // b*NQ + n
  int b = orow / NQ, n = orow % NQ;
  long irow = (long)n * B_BATCH + b;
  float4 x = ((const float4*)(a + irow * 256))[d4];
  float4 y = ((const float4*)(p + irow * 256))[d4];
  short4v o;
  o.x = f2bf(x.x + y.x); o.y = f2bf(x.y + y.y);
  o.z = f2bf(x.z + y.z); o.w = f2bf(x.w + y.w);
  ((short4v*)(out + (long)orow * 256))[d4] = o;
}

// memory (S,B,D) fp32 -> mem_bt (B,S,D) bf16
__global__ __launch_bounds__(256) void memconv_kernel(
    const float* __restrict__ mem, short* __restrict__ out) {
  int t = blockIdx.x * 256 + threadIdx.x;    // (B*S*256)/4 threads
  int d4 = t & 63;
  int row = t >> 6;                          // b*S + s
  int b = row / S_TOT, s = row - b * S_TOT;
  float4 f = ((const float4*)(mem + ((long)s * B_BATCH + b) * 256))[d4];
  short4v o;
  o.x = f2bf(f.x); o.y = f2bf(f.y); o.z = f2bf(f.z); o.w = f2bf(f.w);
  ((short4v*)(out + (long)row * 256))[d4] = o;
}

// ---------------- bf16 MFMA GEMM: C[M,N] = A[M,K] @ W[N,K]^T + bias ----------------
// A,W pre-converted bf16 row-major. 128x128 tile, 4 waves 2x2 of 64x64, BK=32.
// LDS row stride 40 shorts (80B). Requires N%128==0, K%32==0.
template<bool RELU, bool OUTBF>
__global__ __launch_bounds__(256) void gemm_bf16(
    const short* __restrict__ A, const short* __restrict__ W,
    const float* __restrict__ bias, void* __restrict__ Cv,
    int M, int N, int K) {
  __shared__ short As[128 * 40];
  __shared__ short Bs[128 * 40];
  int tid = threadIdx.x;
  int wave = tid >> 6, lane = tid & 63;
  int wm = wave >> 1, wn = wave & 1;
  int quad = lane >> 4, l16 = lane & 15;
  int m0 = blockIdx.y * 128, n0 = blockIdx.x * 128;
  int srow = tid >> 1, shalf = tid & 1;
  int am = m0 + srow;
  bool avalid = am < M;
  const short* asrc = A + (long)(avalid ? am : 0) * K + shalf * 16;
  const short* bsrc = W + (long)(n0 + srow) * K + shalf * 16;
  short* adst = &As[srow * 40 + shalf * 16];
  short* bdst = &Bs[srow * 40 + shalf * 16];
  f32x4 acc[4][4] = {};
  for (int k0 = 0; k0 < K; k0 += 32) {
    short8 ta0 = {}, ta1 = {};
    if (avalid) {
      ta0 = *(const short8*)(asrc + k0);
      ta1 = *(const short8*)(asrc + k0 + 8);
    }
    short8 tb0 = *(const short8*)(bsrc + k0);
    short8 tb1 = *(const short8*)(bsrc + k0 + 8);
    __syncthreads();
    *(short8*)adst = ta0;
    *(short8*)(adst + 8) = ta1;
    *(short8*)bdst = tb0;
    *(short8*)(bdst + 8) = tb1;
    __syncthreads();
    short8 af[4], bf[4];
    #pragma unroll
    for (int i = 0; i < 4; i++) {
      af[i] = *(const short8*)&As[(wm * 64 + i * 16 + l16) * 40 + quad * 8];
      bf[i] = *(const short8*)&Bs[(wn * 64 + i * 16 + l16) * 40 + quad * 8];
    }
    #pragma unroll
    for (int i = 0; i < 4; i++)
      #pragma unroll
      for (int j = 0; j < 4; j++)
        acc[i][j] = __builtin_amdgcn_mfma_f32_16x16x32_bf16(af[i], bf[j], acc[i][j], 0, 0, 0);
  }
  #pragma unroll
  for (int i = 0; i < 4; i++) {
    int mbase = m0 + wm * 64 + i * 16 + quad * 4;
    #pragma unroll
    for (int r = 0; r < 4; r++) {
      int m = mbase + r;
      if (m < M) {
        #pragma unroll
        for (int j = 0; j < 4; j++) {
          int n = n0 + wn * 64 + j * 16 + l16;
          float v = acc[i][j][r] + bias[n];
          if (RELU) v = fmaxf(v, 0.f);
          if (OUTBF) ((short*)Cv)[(long)m * N + n] = f2bf(v);
          else       ((float*)Cv)[(long)m * N + n] = v;
        }
      }
    }
  }
}

// -------------------- self-attention partial: keys split in 2 halves --------------------
// One thread per query; K/V tiles in LDS; lazy-rescale online softmax.
// Writes UNNORMALIZED o + (m,l) state; merge kernel combines halves.
#define KT 64
#define QT 225
#define KHALF 450
__global__ __launch_bounds__(256) void attn_kernel(
    const float* __restrict__ q, const float* __restrict__ k,
    const float* __restrict__ v, float* __restrict__ o0,
    float* __restrict__ o1, float* __restrict__ ml) {
  int bh = blockIdx.y;            // b*8+h
  int b = bh >> 3, h = bh & 7;
  int qt = blockIdx.x;            // 0..3
  int half = blockIdx.z;          // 0..1
  float* opart = half ? o1 : o0;
  int tid = threadIdx.x;
  int myq = qt * QT + tid;
  bool act = tid < QT;
  __shared__ float Ks[KT][36];
  __shared__ float Vs[KT][36];
  const float scale = 0.17677669529663687f;  // 1/sqrt(32)
  float4 qv[8];
  if (act) {
    const float* qp = q + ((long)myq * B_BATCH + b) * 256 + h * 32;
    #pragma unroll
    for (int i = 0; i < 8; i++) {
      float4 t = ((const float4*)qp)[i];
      t.x *= scale; t.y *= scale; t.z *= scale; t.w *= scale;
      qv[i] = t;
    }
  }
  float m = -1e30f, l = 0.f;
  float o[32];
  #pragma unroll
  for (int i = 0; i < 32; i++) o[i] = 0.f;
  int sr = tid >> 2, sj = tid & 3;
  int kstart = half * KHALF, kend = kstart + KHALF;
  for (int k0 = kstart; k0 < kend; k0 += KT) {
    int nk = k0 + sr;
    if (nk < kend) {
      const float* kp = k + ((long)nk * B_BATCH + b) * 256 + h * 32;
      const float* vp = v + ((long)nk * B_BATCH + b) * 256 + h * 32;
      float4 ka = ((const float4*)kp)[sj];
      float4 kb = ((const float4*)kp)[sj + 4];
      float4 va = ((const float4*)vp)[sj];
      float4 vb4 = ((const float4*)vp)[sj + 4];
      *(float4*)&Ks[sr][sj * 4] = ka;
      *(float4*)&Ks[sr][sj * 4 + 16] = kb;
      *(float4*)&Vs[sr][sj * 4] = va;
      *(float4*)&Vs[sr][sj * 4 + 16] = vb4;
    }
    __syncthreads();
    int kn = min(KT, kend - k0);
    if (act) {
      for (int kk = 0; kk < kn; kk++) {
        const float4* kr = (const float4*)&Ks[kk][0];
        float4 k4[8];
        #pragma unroll
        for (int i = 0; i < 8; i++) k4[i] = kr[i];
        float d0 = 0.f, d1 = 0.f, d2 = 0.f, d3 = 0.f;
        #pragma unroll
        for (int i = 0; i < 8; i += 4) {
          d0 += qv[i+0].x*k4[i+0].x + qv[i+0].y*k4[i+0].y + qv[i+0].z*k4[i+0].z + qv[i+0].w*k4[i+0].w;
          d1 += qv[i+1].x*k4[i+1].x + qv[i+1].y*k4[i+1].y + qv[i+1].z*k4[i+1].z + qv[i+1].w*k4[i+1].w;
          d2 += qv[i+2].x*k4[i+2].x + qv[i+2].y*k4[i+2].y + qv[i+2].z*k4[i+2].z + qv[i+2].w*k4[i+2].w;
          d3 += qv[i+3].x*k4[i+3].x + qv[i+3].y*k4[i+3].y + qv[i+3].z*k4[i+3].z + qv[i+3].w*k4[i+3].w;
        }
        float sc = (d0 + d1) + (d2 + d3);
        if (sc > m) {                       // rare: expected ~ln(keys) times
          float corr = __expf(m - sc);
          l *= corr;
          #pragma unroll
          for (int i = 0; i < 32; i++) o[i] *= corr;
          m = sc;
        }
        float p = __expf(sc - m);
        l += p;
        const float4* vr = (const float4*)&Vs[kk][0];
        #pragma unroll
        for (int i = 0; i < 8; i++) {
          float4 v4 = vr[i];
          o[4*i+0] += p * v4.x;
          o[4*i+1] += p * v4.y;
          o[4*i+2] += p * v4.z;
          o[4*i+3] += p * v4.w;
        }
      }
    }
    __syncthreads();
  }
  if (act) {
    float* op = opart + ((long)myq * B_BATCH + b) * 256 + h * 32;
    #pragma unroll
    for (int i = 0; i < 8; i++) {
      float4 t4;
      t4.x = o[4*i+0]; t4.y = o[4*i+1]; t4.z = o[4*i+2]; t4.w = o[4*i+3];
      ((float4*)op)[i] = t4;
    }
    long mli = ((long)(half * 64 + bh) * NQ + myq) * 2;
    ml[mli] = m;
    ml[mli + 1] = l;
  }
}

// merge two attention halves -> att_bf (bf16)
__global__ __launch_bounds__(256) void attn_merge(
    const float* __restrict__ o0, const float* __restrict__ o1,
    const float* __restrict__ ml, short* __restrict__ att) {
  int i = blockIdx.x * 256 + threadIdx.x;  // E elements
  int d = i & 255;
  int row = i >> 8;         // n*B + b
  int n = row >> 3, b = row & 7;
  int h = d >> 5;
  int bh = b * 8 + h;
  long i1 = ((long)bh * NQ + n) * 2;
  long i2 = ((long)(64 + bh) * NQ + n) * 2;
  float m1 = ml[i1], l1 = ml[i1 + 1];
  float m2 = ml[i2], l2 = ml[i2 + 1];
  float M = fmaxf(m1, m2);
  float f1 = __expf(m1 - M), f2 = __expf(m2 - M);
  float L = l1 * f1 + l2 * f2;
  att[i] = f2bf((o0[i] * f1 + o1[i] * f2) / L);
}

// -------------------- residual + layernorm (optional bf16 side output) ------------
template<int BMODE>
__global__ __launch_bounds__(256) void resid_ln(
    const float* __restrict__ X, const float* __restrict__ R,
    const float* __restrict__ g, const float* __restrict__ be,
    float* __restrict__ out, short* __restrict__ obf) {
  int row = blockIdx.x;
  int d = threadIdx.x;
  long rrow;
  if (BMODE == 0) rrow = row;
  else { int b = row % B_BATCH; int n = row / B_BATCH; rrow = (long)b * NQ + n; }
  float x = X[(long)row * 256 + d] + R[rrow * 256 + d];
  float s1 = x, s2 = x * x;
  #pragma unroll
  for (int off = 32; off; off >>= 1) {
    s1 += __shfl_xor(s1, off);
    s2 += __shfl_xor(s2, off);
  }
  __shared__ float a1[4], a2[4];
  int w = d >> 6, lidx = d & 63;
  if (lidx == 0) { a1[w] = s1; a2[w] = s2; }
  __syncthreads();
  float S1 = a1[0] + a1[1] + a1[2] + a1[3];
  float S2 = a2[0] + a2[1] + a2[2] + a2[3];
  float mean = S1 * (1.f / 256.f);
  float var = S2 * (1.f / 256.f) - mean * mean;
  float y = (x - mean) * rsqrtf(var + 1e-5f) * g[d] + be[d];
  out[(long)row * 256 + d] = y;
  if (obf) obf[(long)row * 256 + d] = f2bf(y);
}

// -------------------- deformable-attention sampling (bf16 value, bf16 out) ------------
__global__ __launch_bounds__(256) void deform_sample(
    const unsigned short* __restrict__ value, const float* __restrict__ offs,
    const float* __restrict__ aw, const float* __restrict__ qrp,
    short* __restrict__ samp) {
  int bq = blockIdx.x;  // b*NQ + q
  int b = bq / NQ, q = bq % NQ;
  int h = threadIdx.x >> 5, c = threadIdx.x & 31;
  __shared__ float Wl[8][16], Lx[8][16], Ly[8][16];
  if (c < 16) {
    float a = aw[(long)bq * 128 + h * 16 + c];
    float ox = offs[(long)bq * 256 + (h * 16 + c) * 2 + 0];
    float oy = offs[(long)bq * 256 + (h * 16 + c) * 2 + 1];
    const float* rp = qrp + ((long)q * B_BATCH + b) * 4;
    Lx[h][c] = rp[0] + ox * 0.25f * rp[2] * 0.5f;
    Ly[h][c] = rp[1] + oy * 0.25f * rp[3] * 0.5f;
    Wl[h][c] = a;
  }
  __syncthreads();
  if (threadIdx.x < 8) {
    int hh = threadIdx.x;
    float mx = -1e30f;
    for (int i = 0; i < 16; i++) mx = fmaxf(mx, Wl[hh][i]);
    float sm = 0.f;
    for (int i = 0; i < 16; i++) { float e = __expf(Wl[hh][i] - mx); Wl[hh][i] = e; sm += e; }
    float inv = 1.f / sm;
    for (int i = 0; i < 16; i++) Wl[hh][i] *= inv;
  }
  __syncthreads();
  const int lvlW[4] = {96, 48, 24, 12};
  const int lvlS[4] = {0, 9216, 11520, 12096};
  float acc = 0.f;
  const unsigned short* vb = value + (long)b * S_TOT * 256 + h * 32 + c;
  #pragma unroll
  for (int l = 0; l < 4; l++) {
    int ww = lvlW[l], hh2 = lvlW[l], st = lvlS[l];
    #pragma unroll
    for (int p = 0; p < 4; p++) {
      int lp = l * 4 + p;
      float wgt = Wl[h][lp];
      float x = Lx[h][lp] * ww - 0.5f;
      float y = Ly[h][lp] * hh2 - 0.5f;
      float x0f = floorf(x), y0f = floorf(y);
      float lx = x - x0f, ly = y - y0f;
      int x0 = (int)x0f, y0 = (int)y0f;
      #pragma unroll
      for (int cy = 0; cy < 2; cy++) {
        #pragma unroll
        for (int cx = 0; cx < 2; cx++) {
          int xi = x0 + cx, yi = y0 + cy;
          float cw = (cx ? lx : 1.f - lx) * (cy ? ly : 1.f - ly);
          bool valid = (xi >= 0) && (xi < ww) && (yi >= 0) && (yi < hh2);
          int xc = min(max(xi, 0), ww - 1);
          int yc = min(max(yi, 0), hh2 - 1);
          float vv = bf2f(vb[(long)(st + yc * ww + xc) * 256]);
          acc += (valid ? cw * wgt : 0.f) * vv;
        }
      }
    }
  }
  samp[(long)bq * 256 + h * 32 + c] = f2bf(acc);
}

// -------------------- host launch --------------------
extern "C" void kernel_launch(void* const* d_in, const int* in_sizes, int n_in,
                              void* d_out, int out_size, void* d_ws, size_t ws_size,
                              hipStream_t stream) {
  const float* queries = (const float*)d_in[0];
  const float* qpe     = (const float*)d_in[1];
  const float* qrp     = (const float*)d_in[2];
  const float* memory  = (const float*)d_in[3];
  const float* in_w    = (const float*)d_in[7];
  const float* in_b    = (const float*)d_in[8];
  const float* out_w   = (const float*)d_in[9];
  const float* out_b   = (const float*)d_in[10];
  const float* n1g = (const float*)d_in[11];
  const float* n1b = (const float*)d_in[12];
  const float* n2g = (const float*)d_in[13];
  const float* n2b = (const float*)d_in[14];
  const float* n3g = (const float*)d_in[15];
  const float* n3b = (const float*)d_in[16];
  const float* l1w = (const float*)d_in[17];
  const float* l1b = (const float*)d_in[18];
  const float* l2w = (const float*)d_in[19];
  const float* l2b = (const float*)d_in[20];
  const float* off_w = (const float*)d_in[21];
  const float* off_b = (const float*)d_in[22];
  const float* aw_w  = (const float*)d_in[23];
  const float* aw_b  = (const float*)d_in[24];
  const float* val_w = (const float*)d_in[25];
  const float* val_b = (const float*)d_in[26];
  const float* cout_w = (const float*)d_in[27];
  const float* cout_b = (const float*)d_in[28];

  float* ws = (float*)d_ws;
  const long E = (long)NROW * 256;        // 1,843,200
  // fp32 slots (lifetime-disjoint reuse)
  float* slotA = ws + 0 * E;   // qbuf -> offs
  float* slotB = ws + 1 * E;   // kbuf -> awb
  float* slotC = ws + 2 * E;   // vbuf -> sa -> ca -> ffn
  float* slotE = ws + 3 * E;   // attn o_part half0 -> q2
  float* slotF = ws + 4 * E;   // attn o_part half1 -> q3
  // bf16 slots
  short* bfA = (short*)(ws + 5 * E);  // qk_bf -> ml(attn) -> samp_bf
  short* bfB = bfA + E;               // queries_bf -> qin_bf
  short* bfC = bfB + E;               // att_bf -> q3_bf
  short* wbf = bfC + E;               // 1,540,096 weights bf16
  short* membt = wbf + 1540096;       // (B,S,D) bf16, 25,067,520 -> hidden_bf reuse
  short* valbf = membt + 25067520;    // value bf16, 25,067,520

  short* w_in   = wbf;                 // 196608 (Wq/Wk/Wv)
  short* w_out  = w_in + 196608;
  short* w_off  = w_out + 65536;
  short* w_aw   = w_off + 65536;       // 32768
  short* w_val  = w_aw + 32768;
  short* w_cout = w_val + 65536;
  short* w_l1   = w_cout + 65536;      // 524288
  short* w_l2   = w_l1 + 524288;       // 524288

  dim3 blk(256);
  dim3 g7200(NROW);
  const int E4 = (int)(E / 1024);      // 1800 blocks for x4-vectorized E kernels

  // 0. weights -> bf16 (one fused launch)
  WConvArgs wa;
  wa.src[0] = in_w;  wa.dst[0] = w_in;   int c0 = 196608;
  wa.src[1] = out_w; wa.dst[1] = w_out;  int c1 = 65536;
  wa.src[2] = off_w; wa.dst[2] = w_off;  int c2 = 65536;
  wa.src[3] = aw_w;  wa.dst[3] = w_aw;   int c3 = 32768;
  wa.src[4] = val_w; wa.dst[4] = w_val;  int c4 = 65536;
  wa.src[5] = cout_w;wa.dst[5] = w_cout; int c5 = 65536;
  wa.src[6] = l1w;   wa.dst[6] = w_l1;   int c6 = 524288;
  wa.src[7] = l2w;   wa.dst[7] = w_l2;   int c7 = 524288;
  int acc0 = 0;
  int cs[8] = {c0,c1,c2,c3,c4,c5,c6,c7};
  for (int i = 0; i < 8; i++) { acc0 += cs[i]; wa.end[i] = acc0; }
  wa.total = acc0;
  wconv_kernel<<<dim3((acc0 + 255) / 256), blk, 0, stream>>>(wa);

  // 1. qk_bf = bf16(queries + qpe); queries_bf = bf16(queries)
  addbf_kernel<<<dim3(E4), blk, 0, stream>>>(queries, qpe, bfA);
  conv_kernel<<<dim3(E4), blk, 0, stream>>>(queries, bfB);
  // 2-4. in-proj q,k,v (fp32 out for attn)
  gemm_bf16<false, false><<<dim3(2, 57), blk, 0, stream>>>(bfA, w_in, in_b, slotA, NROW, 256, 256);
  gemm_bf16<false, false><<<dim3(2, 57), blk, 0, stream>>>(bfA, w_in + 65536, in_b + 256, slotB, NROW, 256, 256);
  gemm_bf16<false, false><<<dim3(2, 57), blk, 0, stream>>>(bfB, w_in + 131072, in_b + 512, slotC, NROW, 256, 256);
  // 5. self-attention: 2 key-halves x 4 q-tiles x 64 bh, then merge
  attn_kernel<<<dim3(4, 64, 2), blk, 0, stream>>>(slotA, slotB, slotC, slotE, slotF, (float*)bfA);
  attn_merge<<<g7200, blk, 0, stream>>>(slotE, slotF, (const float*)bfA, bfC);
  // 6. out-proj -> sa (slotC; vbuf dead)
  gemm_bf16<false, false><<<dim3(2, 57), blk, 0, stream>>>(bfC, w_out, out_b, slotC, NROW, 256, 256);
  // 7. q2 = LN(queries + sa) [norm2] -> slotE
  resid_ln<0><<<g7200, blk, 0, stream>>>(queries, slotC, n2g, n2b, slotE, nullptr);
  // 8. qin_bf = bf16((q2 + qpe)^T)
  transaddbf_kernel<<<dim3(E4), blk, 0, stream>>>(slotE, qpe, bfB);
  // 9-10. offsets + attention-weight projections (fp32 out)
  gemm_bf16<false, false><<<dim3(2, 57), blk, 0, stream>>>(bfB, w_off, off_b, slotA, NROW, 256, 256);
  gemm_bf16<false, false><<<dim3(1, 57), blk, 0, stream>>>(bfB, w_aw, aw_b, slotB, NROW, 128, 256);
  // 11. memory -> (B,S,D) bf16; value projection -> bf16
  memconv_kernel<<<dim3(24480), blk, 0, stream>>>(memory, membt);
  gemm_bf16<false, true><<<dim3(2, 765), blk, 0, stream>>>(membt, w_val, val_b, valbf, B_BATCH * S_TOT, 256, 256);
  // 12. deformable sampling -> samp_bf (bfA)
  deform_sample<<<g7200, blk, 0, stream>>>((const unsigned short*)valbf, slotA, slotB, qrp, bfA);
  // 13. cross-attn output proj -> ca (slotC)
  gemm_bf16<false, false><<<dim3(2, 57), blk, 0, stream>>>(bfA, w_cout, cout_b, slotC, NROW, 256, 256);
  // 14. q3 = LN(q2 + ca^T) [norm1] -> slotF (+ bf16 copy in bfC)
  resid_ln<1><<<g7200, blk, 0, stream>>>(slotE, slotC, n1g, n1b, slotF, bfC);
  // 15. FFN lin1 + relu -> hidden bf16 (membt reuse)
  gemm_bf16<true, true><<<dim3(16, 57), blk, 0, stream>>>(bfC, w_l1, l1b, membt, NROW, DFF, 256);
  // 16. FFN lin2 -> ffn (slotC)
  gemm_bf16<false, false><<<dim3(2, 57), blk, 0, stream>>>(membt, w_l2, l2b, slotC, NROW, 256, DFF);
  // 17. out = LN(q3 + ffn) [norm3]
  resid_ln<0><<<g7200, blk, 0, stream>>>(slotF, slotC, n3g, n3b, (float*)d_out, nullptr);
}

// Round 6
// 496.296 us; speedup vs baseline: 4.8681x; 1.3359x over previous
//
#include <hip/hip_runtime.h>
#include <hip/hip_bf16.h>

// Problem constants (fixed by the reference)
#define D_DIM 256
#define H_HEADS 8
#define L_LVLS 4
#define P_PTS 4
#define DFF 2048
#define DH 32
#define NQ 900
#define B_BATCH 8
#define S_TOT 12240
#define NROW (NQ * B_BATCH)   // 7200
#define KPAD 928              // 900 keys padded to 29*32

typedef __attribute__((ext_vector_type(8))) short short8;
typedef __attribute__((ext_vector_type(4))) short short4v;
typedef __attribute__((ext_vector_type(4))) float f32x4;

// float -> bf16 round-to-nearest-even (inputs finite)
__device__ __forceinline__ short f2bf(float x) {
  union { float f; unsigned u; } v; v.f = x;
  unsigned r = v.u + 0x7fff + ((v.u >> 16) & 1);
  return (short)(r >> 16);
}
__device__ __forceinline__ float bf2f(unsigned short u) {
  union { unsigned u; float f; } v; v.u = ((unsigned)u) << 16; return v.f;
}

// -------------------- fused weight conversion fp32->bf16 (8 segments) --------------------
struct WConvArgs {
  const float* src[8];
  short* dst[8];
  int end[8];
  int total;
};
__global__ __launch_bounds__(256) void wconv_kernel(WConvArgs a) {
  int i = blockIdx.x * 256 + threadIdx.x;
  if (i >= a.total) return;
  int seg = 0;
  while (seg < 7 && i >= a.end[seg]) seg++;
  int base = seg ? a.end[seg - 1] : 0;
  a.dst[seg][i - base] = f2bf(a.src[seg][i - base]);
}

// -------------------- c_bf = bf16(a + b), vectorized x4 --------------------
__global__ __launch_bounds__(256) void addbf_kernel(
    const float* __restrict__ a, const float* __restrict__ b, short* __restrict__ c) {
  int t = blockIdx.x * 256 + threadIdx.x;   // E/4 threads
  float4 x = ((const float4*)a)[t];
  float4 y = ((const float4*)b)[t];
  short4v o;
  o.x = f2bf(x.x + y.x); o.y = f2bf(x.y + y.y);
  o.z = f2bf(x.z + y.z); o.w = f2bf(x.w + y.w);
  ((short4v*)c)[t] = o;
}

// -------------------- d_bf = bf16(s), vectorized x4 --------------------
__global__ __launch_bounds__(256) void conv_kernel(
    const float* __restrict__ s, short* __restrict__ d) {
  int t = blockIdx.x * 256 + threadIdx.x;
  float4 x = ((const float4*)s)[t];
  short4v o;
  o.x = f2bf(x.x); o.y = f2bf(x.y); o.z = f2bf(x.z); o.w = f2bf(x.w);
  ((short4v*)d)[t] = o;
}

// qin_bf[b,n,:] = bf16(q2[n,b,:] + qpe[n,b,:])   (transpose + add)
__global__ __launch_bounds__(256) void transaddbf_kernel(
    const float* __restrict__ a, const float* __restrict__ p, short* __restrict__ out) {
  int t = blockIdx.x * 256 + threadIdx.x;   // E/4
  int d4 = t & 63;
  int orow = t >> 6;               // b*NQ + n
  int b = orow / NQ, n = orow % NQ;
  long irow = (long)n * B_BATCH + b;
  float4 x = ((const float4*)(a + irow * 256))[d4];
  float4 y = ((const float4*)(p + irow * 256))[d4];
  short4v o;
  o.x = f2bf(x.x + y.x); o.y = f2bf(x.y + y.y);
  o.z = f2bf(x.z + y.z); o.w = f2bf(x.w + y.w);
  ((short4v*)(out + (long)orow * 256))[d4] = o;
}

// memory (S,B,D) fp32 -> mem_bt (B,S,D) bf16
__global__ __launch_bounds__(256) void memconv_kernel(
    const float* __restrict__ mem, short* __restrict__ out) {
  int t = blockIdx.x * 256 + threadIdx.x;    // (B*S*256)/4 threads
  int d4 = t & 63;
  int row = t >> 6;                          // b*S + s
  int b = row / S_TOT, s = row - b * S_TOT;
  float4 f = ((const float4*)(mem + ((long)s * B_BATCH + b) * 256))[d4];
  short4v o;
  o.x = f2bf(f.x); o.y = f2bf(f.y); o.z = f2bf(f.z); o.w = f2bf(f.w);
  ((short4v*)(out + (long)row * 256))[d4] = o;
}

// ---------------- bf16 MFMA GEMM: C[M,N] = A[M,K] @ W[N,K]^T + bias ----------------
// OMODE 0: fp32 flat.  1: bf16 flat.
// 2: QK head-split: row m = nq*8+b, col n -> buf=n>>8 (0=q scaled by log2e/sqrt32,
//    1=k), out[((buf*64 + b*8+h)*928 + nq)*32 + d], h=(n>>5)&7, d=n&31.
// 3: V transposed: out[((b*8+h)*32 + d)*928 + nq].
template<bool RELU, int OMODE>
__global__ __launch_bounds__(256) void gemm_bf16(
    const short* __restrict__ A, const short* __restrict__ W,
    const float* __restrict__ bias, void* __restrict__ Cv,
    int M, int N, int K) {
  __shared__ short As[128 * 40];
  __shared__ short Bs[128 * 40];
  int tid = threadIdx.x;
  int wave = tid >> 6, lane = tid & 63;
  int wm = wave >> 1, wn = wave & 1;
  int quad = lane >> 4, l16 = lane & 15;
  int m0 = blockIdx.y * 128, n0 = blockIdx.x * 128;
  int srow = tid >> 1, shalf = tid & 1;
  int am = m0 + srow;
  bool avalid = am < M;
  const short* asrc = A + (long)(avalid ? am : 0) * K + shalf * 16;
  const short* bsrc = W + (long)(n0 + srow) * K + shalf * 16;
  short* adst = &As[srow * 40 + shalf * 16];
  short* bdst = &Bs[srow * 40 + shalf * 16];
  f32x4 acc[4][4] = {};
  for (int k0 = 0; k0 < K; k0 += 32) {
    short8 ta0 = {}, ta1 = {};
    if (avalid) {
      ta0 = *(const short8*)(asrc + k0);
      ta1 = *(const short8*)(asrc + k0 + 8);
    }
    short8 tb0 = *(const short8*)(bsrc + k0);
    short8 tb1 = *(const short8*)(bsrc + k0 + 8);
    __syncthreads();
    *(short8*)adst = ta0;
    *(short8*)(adst + 8) = ta1;
    *(short8*)bdst = tb0;
    *(short8*)(bdst + 8) = tb1;
    __syncthreads();
    short8 af[4], bf[4];
    #pragma unroll
    for (int i = 0; i < 4; i++) {
      af[i] = *(const short8*)&As[(wm * 64 + i * 16 + l16) * 40 + quad * 8];
      bf[i] = *(const short8*)&Bs[(wn * 64 + i * 16 + l16) * 40 + quad * 8];
    }
    #pragma unroll
    for (int i = 0; i < 4; i++)
      #pragma unroll
      for (int j = 0; j < 4; j++)
        acc[i][j] = __builtin_amdgcn_mfma_f32_16x16x32_bf16(af[i], bf[j], acc[i][j], 0, 0, 0);
  }
  #pragma unroll
  for (int i = 0; i < 4; i++) {
    int mbase = m0 + wm * 64 + i * 16 + quad * 4;
    #pragma unroll
    for (int r = 0; r < 4; r++) {
      int m = mbase + r;
      if (m < M) {
        #pragma unroll
        for (int j = 0; j < 4; j++) {
          int n = n0 + wn * 64 + j * 16 + l16;
          float v = acc[i][j][r] + bias[n];
          if (RELU) v = fmaxf(v, 0.f);
          if (OMODE == 0) {
            ((float*)Cv)[(long)m * N + n] = v;
          } else if (OMODE == 1) {
            ((short*)Cv)[(long)m * N + n] = f2bf(v);
          } else if (OMODE == 2) {
            int nq = m >> 3, bb = m & 7;
            int buf = n >> 8, hh = (n >> 5) & 7, dd = n & 31;
            if (buf == 0) v *= 0.25503483f;   // log2(e)/sqrt(32)
            ((short*)Cv)[((long)(buf * 64 + bb * 8 + hh) * KPAD + nq) * 32 + dd] = f2bf(v);
          } else {
            int nq = m >> 3, bb = m & 7;
            int hh = n >> 5, dd = n & 31;
            ((short*)Cv)[((long)(bb * 8 + hh) * 32 + dd) * KPAD + nq] = f2bf(v);
          }
        }
      }
    }
  }
}

// -------------------- MFMA flash self-attention --------------------
// qk_h: [2][64][928][32] bf16 (Q pre-scaled by log2e/sqrt(32)); vT: [64][32][928] bf16.
// Grid (8 qtiles, 64 bh), 256 threads. Per wave: 32 queries; K-loop over 29 32-key
// tiles; S^T = K.Q^T (4 MFMA), p=exp2(s) (scores bounded, no max tracking), P packed
// to per-wave LDS, O^T += Vt.P (4 MFMA). No __syncthreads anywhere.
__global__ __launch_bounds__(256) void attn_mfma(
    const short* __restrict__ qk_h, const short* __restrict__ vT,
    short* __restrict__ att) {
  int bh = blockIdx.y; int b = bh >> 3, h = bh & 7;
  int tid = threadIdx.x; int wave = tid >> 6, lane = tid & 63;
  int quad = lane >> 4, l16 = lane & 15;
  int q0 = blockIdx.x * 128 + wave * 32;
  const short* qb = qk_h + (long)bh * KPAD * 32;
  const short* kb = qk_h + (long)(64 + bh) * KPAD * 32;
  const short* vb = vT + (long)bh * 32 * KPAD;
  __shared__ short P[4][32][40];
  short8 qfr[2];
  #pragma unroll
  for (int i = 0; i < 2; i++) {
    int qrow = q0 + i * 16 + l16; if (qrow > 927) qrow = 927;
    qfr[i] = *(const short8*)(qb + (long)qrow * 32 + quad * 8);
  }
  f32x4 acc[2][2] = {};
  float lsum[2] = {0.f, 0.f};
  const f32x4 zero = {0.f, 0.f, 0.f, 0.f};
  // prefetch tile 0
  short8 ka = *(const short8*)(kb + (long)l16 * 32 + quad * 8);
  short8 kc = *(const short8*)(kb + (long)(16 + l16) * 32 + quad * 8);
  short8 va = *(const short8*)(vb + (long)l16 * KPAD + quad * 8);
  short8 vc = *(const short8*)(vb + (long)(16 + l16) * KPAD + quad * 8);
  for (int t = 0; t < 29; t++) {
    int k0 = t * 32;
    int kn = (t < 28) ? k0 + 32 : k0;
    short8 nka = *(const short8*)(kb + (long)(kn + l16) * 32 + quad * 8);
    short8 nkc = *(const short8*)(kb + (long)(kn + 16 + l16) * 32 + quad * 8);
    short8 nva = *(const short8*)(vb + (long)l16 * KPAD + kn + quad * 8);
    short8 nvc = *(const short8*)(vb + (long)(16 + l16) * KPAD + kn + quad * 8);
    f32x4 s[2][2];
    s[0][0] = __builtin_amdgcn_mfma_f32_16x16x32_bf16(ka, qfr[0], zero, 0, 0, 0);
    s[0][1] = __builtin_amdgcn_mfma_f32_16x16x32_bf16(ka, qfr[1], zero, 0, 0, 0);
    s[1][0] = __builtin_amdgcn_mfma_f32_16x16x32_bf16(kc, qfr[0], zero, 0, 0, 0);
    s[1][1] = __builtin_amdgcn_mfma_f32_16x16x32_bf16(kc, qfr[1], zero, 0, 0, 0);
    float p[2][2][4];
    #pragma unroll
    for (int kf = 0; kf < 2; kf++)
      #pragma unroll
      for (int qf = 0; qf < 2; qf++)
        #pragma unroll
        for (int r = 0; r < 4; r++) {
          float pe = __builtin_amdgcn_exp2f(s[kf][qf][r]);
          if (t == 28) {
            int kid = k0 + kf * 16 + quad * 4 + r;
            if (kid >= 900) pe = 0.f;
          }
          p[kf][qf][r] = pe;
          lsum[qf] += pe;
        }
    // pack p pairs -> P[wave][q][k] bf16 (truncating round, p in [0,1])
    #pragma unroll
    for (int kf = 0; kf < 2; kf++)
      #pragma unroll
      for (int qf = 0; qf < 2; qf++)
        #pragma unroll
        for (int r = 0; r < 4; r += 2) {
          unsigned ua = __float_as_uint(p[kf][qf][r]) + 0x7fffu;
          unsigned ub = __float_as_uint(p[kf][qf][r + 1]) + 0x7fffu;
          unsigned pk = (ua >> 16) | (ub & 0xffff0000u);
          *(unsigned*)&P[wave][qf * 16 + l16][kf * 16 + quad * 4 + r] = pk;
        }
    #pragma unroll
    for (int qf = 0; qf < 2; qf++) {
      short8 pf = *(const short8*)&P[wave][qf * 16 + l16][quad * 8];
      acc[0][qf] = __builtin_amdgcn_mfma_f32_16x16x32_bf16(va, pf, acc[0][qf], 0, 0, 0);
      acc[1][qf] = __builtin_amdgcn_mfma_f32_16x16x32_bf16(vc, pf, acc[1][qf], 0, 0, 0);
    }
    ka = nka; kc = nkc; va = nva; vc = nvc;
  }
  #pragma unroll
  for (int qf = 0; qf < 2; qf++) {
    lsum[qf] += __shfl_xor(lsum[qf], 16);
    lsum[qf] += __shfl_xor(lsum[qf], 32);
  }
  #pragma unroll
  for (int df = 0; df < 2; df++)
    #pragma unroll
    for (int qf = 0; qf < 2; qf++) {
      int qg = q0 + qf * 16 + l16;
      if (qg < 900) {
        float inv = 1.f / lsum[qf];
        int d0 = df * 16 + quad * 4;
        short4v o4;
        o4.x = f2bf(acc[df][qf][0] * inv);
        o4.y = f2bf(acc[df][qf][1] * inv);
        o4.z = f2bf(acc[df][qf][2] * inv);
        o4.w = f2bf(acc[df][qf][3] * inv);
        *(short4v*)(att + (long)(qg * 8 + b) * 256 + h * 32 + d0) = o4;
      }
    }
}

// -------------------- residual + layernorm (optional bf16 side output) ------------
template<int BMODE>
__global__ __launch_bounds__(256) void resid_ln(
    const float* __restrict__ X, const float* __restrict__ R,
    const float* __restrict__ g, const float* __restrict__ be,
    float* __restrict__ out, short* __restrict__ obf) {
  int row = blockIdx.x;
  int d = threadIdx.x;
  long rrow;
  if (BMODE == 0) rrow = row;
  else { int b = row % B_BATCH; int n = row / B_BATCH; rrow = (long)b * NQ + n; }
  float x = X[(long)row * 256 + d] + R[rrow * 256 + d];
  float s1 = x, s2 = x * x;
  #pragma unroll
  for (int off = 32; off; off >>= 1) {
    s1 += __shfl_xor(s1, off);
    s2 += __shfl_xor(s2, off);
  }
  __shared__ float a1[4], a2[4];
  int w = d >> 6, lidx = d & 63;
  if (lidx == 0) { a1[w] = s1; a2[w] = s2; }
  __syncthreads();
  float S1 = a1[0] + a1[1] + a1[2] + a1[3];
  float S2 = a2[0] + a2[1] + a2[2] + a2[3];
  float mean = S1 * (1.f / 256.f);
  float var = S2 * (1.f / 256.f) - mean * mean;
  float y = (x - mean) * rsqrtf(var + 1e-5f) * g[d] + be[d];
  out[(long)row * 256 + d] = y;
  if (obf) obf[(long)row * 256 + d] = f2bf(y);
}

// -------------------- deformable-attention sampling (bf16 value, bf16 out) ------------
__global__ __launch_bounds__(256) void deform_sample(
    const unsigned short* __restrict__ value, const float* __restrict__ offs,
    const float* __restrict__ aw, const float* __restrict__ qrp,
    short* __restrict__ samp) {
  int bq = blockIdx.x;  // b*NQ + q
  int b = bq / NQ, q = bq % NQ;
  int h = threadIdx.x >> 5, c = threadIdx.x & 31;
  __shared__ float Wl[8][16], Lx[8][16], Ly[8][16];
  if (c < 16) {
    float a = aw[(long)bq * 128 + h * 16 + c];
    float ox = offs[(long)bq * 256 + (h * 16 + c) * 2 + 0];
    float oy = offs[(long)bq * 256 + (h * 16 + c) * 2 + 1];
    const float* rp = qrp + ((long)q * B_BATCH + b) * 4;
    Lx[h][c] = rp[0] + ox * 0.25f * rp[2] * 0.5f;
    Ly[h][c] = rp[1] + oy * 0.25f * rp[3] * 0.5f;
    Wl[h][c] = a;
  }
  __syncthreads();
  if (threadIdx.x < 8) {
    int hh = threadIdx.x;
    float mx = -1e30f;
    for (int i = 0; i < 16; i++) mx = fmaxf(mx, Wl[hh][i]);
    float sm = 0.f;
    for (int i = 0; i < 16; i++) { float e = __expf(Wl[hh][i] - mx); Wl[hh][i] = e; sm += e; }
    float inv = 1.f / sm;
    for (int i = 0; i < 16; i++) Wl[hh][i] *= inv;
  }
  __syncthreads();
  const int lvlW[4] = {96, 48, 24, 12};
  const int lvlS[4] = {0, 9216, 11520, 12096};
  float acc = 0.f;
  const unsigned short* vb = value + (long)b * S_TOT * 256 + h * 32 + c;
  #pragma unroll
  for (int l = 0; l < 4; l++) {
    int ww = lvlW[l], hh2 = lvlW[l], st = lvlS[l];
    #pragma unroll
    for (int p = 0; p < 4; p++) {
      int lp = l * 4 + p;
      float wgt = Wl[h][lp];
      float x = Lx[h][lp] * ww - 0.5f;
      float y = Ly[h][lp] * hh2 - 0.5f;
      float x0f = floorf(x), y0f = floorf(y);
      float lx = x - x0f, ly = y - y0f;
      int x0 = (int)x0f, y0 = (int)y0f;
      #pragma unroll
      for (int cy = 0; cy < 2; cy++) {
        #pragma unroll
        for (int cx = 0; cx < 2; cx++) {
          int xi = x0 + cx, yi = y0 + cy;
          float cw = (cx ? lx : 1.f - lx) * (cy ? ly : 1.f - ly);
          bool valid = (xi >= 0) && (xi < ww) && (yi >= 0) && (yi < hh2);
          int xc = min(max(xi, 0), ww - 1);
          int yc = min(max(yi, 0), hh2 - 1);
          float vv = bf2f(vb[(long)(st + yc * ww + xc) * 256]);
          acc += (valid ? cw * wgt : 0.f) * vv;
        }
      }
    }
  }
  samp[(long)bq * 256 + h * 32 + c] = f2bf(acc);
}

// -------------------- host launch --------------------
extern "C" void kernel_launch(void* const* d_in, const int* in_sizes, int n_in,
                              void* d_out, int out_size, void* d_ws, size_t ws_size,
                              hipStream_t stream) {
  const float* queries = (const float*)d_in[0];
  const float* qpe     = (const float*)d_in[1];
  const float* qrp     = (const float*)d_in[2];
  const float* memory  = (const float*)d_in[3];
  const float* in_w    = (const float*)d_in[7];
  const float* in_b    = (const float*)d_in[8];
  const float* out_w   = (const float*)d_in[9];
  const float* out_b   = (const float*)d_in[10];
  const float* n1g = (const float*)d_in[11];
  const float* n1b = (const float*)d_in[12];
  const float* n2g = (const float*)d_in[13];
  const float* n2b = (const float*)d_in[14];
  const float* n3g = (const float*)d_in[15];
  const float* n3b = (const float*)d_in[16];
  const float* l1w = (const float*)d_in[17];
  const float* l1b = (const float*)d_in[18];
  const float* l2w = (const float*)d_in[19];
  const float* l2b = (const float*)d_in[20];
  const float* off_w = (const float*)d_in[21];
  const float* off_b = (const float*)d_in[22];
  const float* aw_w  = (const float*)d_in[23];
  const float* aw_b  = (const float*)d_in[24];
  const float* val_w = (const float*)d_in[25];
  const float* val_b = (const float*)d_in[26];
  const float* cout_w = (const float*)d_in[27];
  const float* cout_b = (const float*)d_in[28];

  float* ws = (float*)d_ws;
  const long E = (long)NROW * 256;        // 1,843,200
  float* slotA = ws + 0 * E;   // offs
  float* slotB = ws + 1 * E;   // awb
  float* slotC = ws + 2 * E;   // sa -> ca -> ffn
  float* slotE = ws + 3 * E;   // q2
  float* slotF = ws + 4 * E;   // q3
  short* bfA = (short*)(ws + 5 * E);  // qk_bf -> samp_bf
  short* bfB = bfA + E;               // queries_bf -> qin_bf
  short* bfC = bfB + E;               // att_bf -> q3_bf
  short* wbf = bfC + E;               // 1,540,096 weights bf16
  short* membt = wbf + 1540096;       // (B,S,D) bf16 25,067,520; attn qk_h/vT live here first
  short* valbf = membt + 25067520;    // value bf16

  short* qk_h = membt;                          // [2][64][928][32] = 3,801,088
  short* vT   = membt + 2L * 64 * KPAD * 32;    // [64][32][928]   = 1,900,544

  short* w_in   = wbf;                 // 196608 (Wq/Wk/Wv)
  short* w_out  = w_in + 196608;
  short* w_off  = w_out + 65536;
  short* w_aw   = w_off + 65536;       // 32768
  short* w_val  = w_aw + 32768;
  short* w_cout = w_val + 65536;
  short* w_l1   = w_cout + 65536;      // 524288
  short* w_l2   = w_l1 + 524288;       // 524288

  dim3 blk(256);
  dim3 g7200(NROW);
  const int E4 = (int)(E / 1024);      // 1800

  // 0. weights -> bf16
  WConvArgs wa;
  wa.src[0] = in_w;  wa.dst[0] = w_in;
  wa.src[1] = out_w; wa.dst[1] = w_out;
  wa.src[2] = off_w; wa.dst[2] = w_off;
  wa.src[3] = aw_w;  wa.dst[3] = w_aw;
  wa.src[4] = val_w; wa.dst[4] = w_val;
  wa.src[5] = cout_w;wa.dst[5] = w_cout;
  wa.src[6] = l1w;   wa.dst[6] = w_l1;
  wa.src[7] = l2w;   wa.dst[7] = w_l2;
  int cs[8] = {196608, 65536, 65536, 32768, 65536, 65536, 524288, 524288};
  int acc0 = 0;
  for (int i = 0; i < 8; i++) { acc0 += cs[i]; wa.end[i] = acc0; }
  wa.total = acc0;
  wconv_kernel<<<dim3((acc0 + 255) / 256), blk, 0, stream>>>(wa);

  // 1. qk_bf = bf16(queries + qpe); queries_bf = bf16(queries)
  addbf_kernel<<<dim3(E4), blk, 0, stream>>>(queries, qpe, bfA);
  conv_kernel<<<dim3(E4), blk, 0, stream>>>(queries, bfB);
  // 2. in-proj Q+K fused (N=512) -> head-split qk_h; V -> transposed vT
  gemm_bf16<false, 2><<<dim3(4, 57), blk, 0, stream>>>(bfA, w_in, in_b, qk_h, NROW, 512, 256);
  gemm_bf16<false, 3><<<dim3(2, 57), blk, 0, stream>>>(bfB, w_in + 131072, in_b + 512, vT, NROW, 256, 256);
  // 3. MFMA flash self-attention -> att_bf (bfC)
  attn_mfma<<<dim3(8, 64), blk, 0, stream>>>(qk_h, vT, bfC);
  // 4. out-proj -> sa (slotC)
  gemm_bf16<false, 0><<<dim3(2, 57), blk, 0, stream>>>(bfC, w_out, out_b, slotC, NROW, 256, 256);
  // 5. q2 = LN(queries + sa) [norm2] -> slotE
  resid_ln<0><<<g7200, blk, 0, stream>>>(queries, slotC, n2g, n2b, slotE, nullptr);
  // 6. qin_bf = bf16((q2 + qpe)^T)
  transaddbf_kernel<<<dim3(E4), blk, 0, stream>>>(slotE, qpe, bfB);
  // 7. offsets + attention-weight projections (fp32 out)
  gemm_bf16<false, 0><<<dim3(2, 57), blk, 0, stream>>>(bfB, w_off, off_b, slotA, NROW, 256, 256);
  gemm_bf16<false, 0><<<dim3(1, 57), blk, 0, stream>>>(bfB, w_aw, aw_b, slotB, NROW, 128, 256);
  // 8. memory -> (B,S,D) bf16 (overwrites qk_h/vT; attn already done); value proj -> bf16
  memconv_kernel<<<dim3(24480), blk, 0, stream>>>(memory, membt);
  gemm_bf16<false, 1><<<dim3(2, 765), blk, 0, stream>>>(membt, w_val, val_b, valbf, B_BATCH * S_TOT, 256, 256);
  // 9. deformable sampling -> samp_bf (bfA)
  deform_sample<<<g7200, blk, 0, stream>>>((const unsigned short*)valbf, slotA, slotB, qrp, bfA);
  // 10. cross-attn output proj -> ca (slotC)
  gemm_bf16<false, 0><<<dim3(2, 57), blk, 0, stream>>>(bfA, w_cout, cout_b, slotC, NROW, 256, 256);
  // 11. q3 = LN(q2 + ca^T) [norm1] -> slotF (+ bf16 copy in bfC)
  resid_ln<1><<<g7200, blk, 0, stream>>>(slotE, slotC, n1g, n1b, slotF, bfC);
  // 12. FFN lin1 + relu -> hidden bf16 (membt reuse)
  gemm_bf16<true, 1><<<dim3(16, 57), blk, 0, stream>>>(bfC, w_l1, l1b, membt, NROW, DFF, 256);
  // 13. FFN lin2 -> ffn (slotC)
  gemm_bf16<false, 0><<<dim3(2, 57), blk, 0, stream>>>(membt, w_l2, l2b, slotC, NROW, 256, DFF);
  // 14. out = LN(q3 + ffn) [norm3]
  resid_ln<0><<<g7200, blk, 0, stream>>>(slotF, slotC, n3g, n3b, (float*)d_out, nullptr);
}

// Round 7
// 445.226 us; speedup vs baseline: 5.4265x; 1.1147x over previous
//
#include <hip/hip_runtime.h>
#include <hip/hip_bf16.h>

// Problem constants (fixed by the reference)
#define D_DIM 256
#define H_HEADS 8
#define L_LVLS 4
#define P_PTS 4
#define DFF 2048
#define DH 32
#define NQ 900
#define B_BATCH 8
#define S_TOT 12240
#define NROW (NQ * B_BATCH)   // 7200
#define KPAD 928              // 900 keys padded to 29*32

typedef __attribute__((ext_vector_type(8))) short short8;
typedef __attribute__((ext_vector_type(4))) short short4v;
typedef __attribute__((ext_vector_type(4))) float f32x4;

// float -> bf16 round-to-nearest-even (inputs finite)
__device__ __forceinline__ short f2bf(float x) {
  union { float f; unsigned u; } v; v.f = x;
  unsigned r = v.u + 0x7fff + ((v.u >> 16) & 1);
  return (short)(r >> 16);
}
__device__ __forceinline__ float bf2f(unsigned short u) {
  union { unsigned u; float f; } v; v.u = ((unsigned)u) << 16; return v.f;
}

// -------------------- fused weight conversion fp32->bf16 (8 segments) --------------------
struct WConvArgs {
  const float* src[8];
  short* dst[8];
  int end[8];
  int total;
};
__global__ __launch_bounds__(256) void wconv_kernel(WConvArgs a) {
  int i = blockIdx.x * 256 + threadIdx.x;
  if (i >= a.total) return;
  int seg = 0;
  while (seg < 7 && i >= a.end[seg]) seg++;
  int base = seg ? a.end[seg - 1] : 0;
  a.dst[seg][i - base] = f2bf(a.src[seg][i - base]);
}

// qk_bf = bf16(q + p); q_bf = bf16(q)   (one pass)
__global__ __launch_bounds__(256) void addconv_kernel(
    const float* __restrict__ q, const float* __restrict__ p,
    short* __restrict__ qk_bf, short* __restrict__ q_bf) {
  int t = blockIdx.x * 256 + threadIdx.x;   // E/4 threads
  float4 x = ((const float4*)q)[t];
  float4 y = ((const float4*)p)[t];
  short4v s, a;
  s.x = f2bf(x.x); s.y = f2bf(x.y); s.z = f2bf(x.z); s.w = f2bf(x.w);
  a.x = f2bf(x.x + y.x); a.y = f2bf(x.y + y.y);
  a.z = f2bf(x.z + y.z); a.w = f2bf(x.w + y.w);
  ((short4v*)q_bf)[t] = s;
  ((short4v*)qk_bf)[t] = a;
}

// ---------------- bf16 MFMA GEMM: C[M,N] = A[M,K] @ W[N,K]^T + bias ----------------
// TM = 128 (4 waves x 64x64) or 64 (4 waves x 32x64).  BN = 128.
// OMODE 0: fp32 flat (row stride LDC).  1: bf16 flat (LDC).
// 2: QK head-split: m = nq*8+b, buf=n>>8 (0=q scaled by log2e/sqrt32, 1=k),
//    out[((buf*64 + b*8+h)*928 + nq)*32 + d], h=(n>>5)&7, d=n&31.
// 3: V transposed: out[((b*8+h)*32 + d)*928 + nq].
template<bool RELU, int OMODE, int TM>
__global__ __launch_bounds__(256) void gemm_bf16(
    const short* __restrict__ A, const short* __restrict__ W,
    const float* __restrict__ bias, void* __restrict__ Cv,
    int M, int N, int K, int LDC) {
  constexpr int MI = (TM == 128) ? 4 : 2;
  __shared__ short As[TM * 40];
  __shared__ short Bs[128 * 40];
  int tid = threadIdx.x;
  int wave = tid >> 6, lane = tid & 63;
  int wm = wave >> 1, wn = wave & 1;
  int quad = lane >> 4, l16 = lane & 15;
  int m0 = blockIdx.y * TM, n0 = blockIdx.x * 128;
  int srowB = tid >> 1, shalfB = tid & 1;
  const short* bsrc = W + (long)(n0 + srowB) * K + shalfB * 16;
  short* bdst = &Bs[srowB * 40 + shalfB * 16];
  const short* asrc; short* adst; bool avalid;
  if (TM == 128) {
    int srow = tid >> 1, shalf = tid & 1;
    int am = m0 + srow;
    avalid = am < M;
    asrc = A + (long)(avalid ? am : 0) * K + shalf * 16;
    adst = &As[srow * 40 + shalf * 16];
  } else {
    int srow = tid >> 2, spart = tid & 3;
    int am = m0 + srow;
    avalid = am < M;
    asrc = A + (long)(avalid ? am : 0) * K + spart * 8;
    adst = &As[srow * 40 + spart * 8];
  }
  f32x4 acc[MI][4] = {};
  for (int k0 = 0; k0 < K; k0 += 32) {
    short8 ta0 = {}, ta1 = {};
    if (avalid) {
      ta0 = *(const short8*)(asrc + k0);
      if (TM == 128) ta1 = *(const short8*)(asrc + k0 + 8);
    }
    short8 tb0 = *(const short8*)(bsrc + k0);
    short8 tb1 = *(const short8*)(bsrc + k0 + 8);
    __syncthreads();
    *(short8*)adst = ta0;
    if (TM == 128) *(short8*)(adst + 8) = ta1;
    *(short8*)bdst = tb0;
    *(short8*)(bdst + 8) = tb1;
    __syncthreads();
    short8 af[MI], bf[4];
    #pragma unroll
    for (int i = 0; i < MI; i++)
      af[i] = *(const short8*)&As[(wm * (TM / 2) + i * 16 + l16) * 40 + quad * 8];
    #pragma unroll
    for (int j = 0; j < 4; j++)
      bf[j] = *(const short8*)&Bs[(wn * 64 + j * 16 + l16) * 40 + quad * 8];
    #pragma unroll
    for (int i = 0; i < MI; i++)
      #pragma unroll
      for (int j = 0; j < 4; j++)
        acc[i][j] = __builtin_amdgcn_mfma_f32_16x16x32_bf16(af[i], bf[j], acc[i][j], 0, 0, 0);
  }
  #pragma unroll
  for (int i = 0; i < MI; i++) {
    int mbase = m0 + wm * (TM / 2) + i * 16 + quad * 4;
    #pragma unroll
    for (int r = 0; r < 4; r++) {
      int m = mbase + r;
      if (m < M) {
        #pragma unroll
        for (int j = 0; j < 4; j++) {
          int n = n0 + wn * 64 + j * 16 + l16;
          float v = acc[i][j][r] + bias[n];
          if (RELU) v = fmaxf(v, 0.f);
          if (OMODE == 0) {
            ((float*)Cv)[(long)m * LDC + n] = v;
          } else if (OMODE == 1) {
            ((short*)Cv)[(long)m * LDC + n] = f2bf(v);
          } else if (OMODE == 2) {
            int nq = m >> 3, bb = m & 7;
            int buf = n >> 8, hh = (n >> 5) & 7, dd = n & 31;
            if (buf == 0) v *= 0.25503483f;   // log2(e)/sqrt(32)
            ((short*)Cv)[((long)(buf * 64 + bb * 8 + hh) * KPAD + nq) * 32 + dd] = f2bf(v);
          } else {
            int nq = m >> 3, bb = m & 7;
            int hh = n >> 5, dd = n & 31;
            ((short*)Cv)[((long)(bb * 8 + hh) * 32 + dd) * KPAD + nq] = f2bf(v);
          }
        }
      }
    }
  }
}

// ---------------- value GEMM: fp32 A in (S,B,D), fused bf16 conv, bf16 out ------------
// output row m = b*S + s reads A row s*B + b.  M=97920, N=256, K=256, TM=128.
__global__ __launch_bounds__(256) void gemm_val(
    const float* __restrict__ A, const short* __restrict__ W,
    const float* __restrict__ bias, short* __restrict__ C) {
  __shared__ short As[128 * 40];
  __shared__ short Bs[128 * 40];
  int tid = threadIdx.x;
  int wave = tid >> 6, lane = tid & 63;
  int wm = wave >> 1, wn = wave & 1;
  int quad = lane >> 4, l16 = lane & 15;
  int m0 = blockIdx.y * 128, n0 = blockIdx.x * 128;
  int srow = tid >> 1, shalf = tid & 1;
  int am = m0 + srow;
  int b = am / S_TOT, s = am - b * S_TOT;
  const float* asrc = A + ((long)s * B_BATCH + b) * 256 + shalf * 16;
  const short* bsrc = W + (long)(n0 + srow) * 256 + shalf * 16;
  short* adst = &As[srow * 40 + shalf * 16];
  short* bdst = &Bs[srow * 40 + shalf * 16];
  f32x4 acc[4][4] = {};
  for (int k0 = 0; k0 < 256; k0 += 32) {
    float4 f0 = ((const float4*)(asrc + k0))[0];
    float4 f1 = ((const float4*)(asrc + k0))[1];
    float4 f2 = ((const float4*)(asrc + k0))[2];
    float4 f3 = ((const float4*)(asrc + k0))[3];
    short8 ta0, ta1;
    ta0[0]=f2bf(f0.x); ta0[1]=f2bf(f0.y); ta0[2]=f2bf(f0.z); ta0[3]=f2bf(f0.w);
    ta0[4]=f2bf(f1.x); ta0[5]=f2bf(f1.y); ta0[6]=f2bf(f1.z); ta0[7]=f2bf(f1.w);
    ta1[0]=f2bf(f2.x); ta1[1]=f2bf(f2.y); ta1[2]=f2bf(f2.z); ta1[3]=f2bf(f2.w);
    ta1[4]=f2bf(f3.x); ta1[5]=f2bf(f3.y); ta1[6]=f2bf(f3.z); ta1[7]=f2bf(f3.w);
    short8 tb0 = *(const short8*)(bsrc + k0);
    short8 tb1 = *(const short8*)(bsrc + k0 + 8);
    __syncthreads();
    *(short8*)adst = ta0;
    *(short8*)(adst + 8) = ta1;
    *(short8*)bdst = tb0;
    *(short8*)(bdst + 8) = tb1;
    __syncthreads();
    short8 af[4], bf[4];
    #pragma unroll
    for (int i = 0; i < 4; i++) {
      af[i] = *(const short8*)&As[(wm * 64 + i * 16 + l16) * 40 + quad * 8];
      bf[i] = *(const short8*)&Bs[(wn * 64 + i * 16 + l16) * 40 + quad * 8];
    }
    #pragma unroll
    for (int i = 0; i < 4; i++)
      #pragma unroll
      for (int j = 0; j < 4; j++)
        acc[i][j] = __builtin_amdgcn_mfma_f32_16x16x32_bf16(af[i], bf[j], acc[i][j], 0, 0, 0);
  }
  #pragma unroll
  for (int i = 0; i < 4; i++) {
    int mbase = m0 + wm * 64 + i * 16 + quad * 4;
    #pragma unroll
    for (int r = 0; r < 4; r++) {
      int m = mbase + r;
      #pragma unroll
      for (int j = 0; j < 4; j++) {
        int n = n0 + wn * 64 + j * 16 + l16;
        C[(long)m * 256 + n] = f2bf(acc[i][j][r] + bias[n]);
      }
    }
  }
}

// -------------------- MFMA flash self-attention --------------------
__global__ __launch_bounds__(256) void attn_mfma(
    const short* __restrict__ qk_h, const short* __restrict__ vT,
    short* __restrict__ att) {
  int bh = blockIdx.y; int b = bh >> 3, h = bh & 7;
  int tid = threadIdx.x; int wave = tid >> 6, lane = tid & 63;
  int quad = lane >> 4, l16 = lane & 15;
  int q0 = blockIdx.x * 128 + wave * 32;
  const short* qb = qk_h + (long)bh * KPAD * 32;
  const short* kb = qk_h + (long)(64 + bh) * KPAD * 32;
  const short* vb = vT + (long)bh * 32 * KPAD;
  __shared__ short P[4][32][40];
  short8 qfr[2];
  #pragma unroll
  for (int i = 0; i < 2; i++) {
    int qrow = q0 + i * 16 + l16; if (qrow > 927) qrow = 927;
    qfr[i] = *(const short8*)(qb + (long)qrow * 32 + quad * 8);
  }
  f32x4 acc[2][2] = {};
  float lsum[2] = {0.f, 0.f};
  const f32x4 zero = {0.f, 0.f, 0.f, 0.f};
  short8 ka = *(const short8*)(kb + (long)l16 * 32 + quad * 8);
  short8 kc = *(const short8*)(kb + (long)(16 + l16) * 32 + quad * 8);
  short8 va = *(const short8*)(vb + (long)l16 * KPAD + quad * 8);
  short8 vc = *(const short8*)(vb + (long)(16 + l16) * KPAD + quad * 8);
  for (int t = 0; t < 29; t++) {
    int k0 = t * 32;
    int kn = (t < 28) ? k0 + 32 : k0;
    short8 nka = *(const short8*)(kb + (long)(kn + l16) * 32 + quad * 8);
    short8 nkc = *(const short8*)(kb + (long)(kn + 16 + l16) * 32 + quad * 8);
    short8 nva = *(const short8*)(vb + (long)l16 * KPAD + kn + quad * 8);
    short8 nvc = *(const short8*)(vb + (long)(16 + l16) * KPAD + kn + quad * 8);
    f32x4 s[2][2];
    s[0][0] = __builtin_amdgcn_mfma_f32_16x16x32_bf16(ka, qfr[0], zero, 0, 0, 0);
    s[0][1] = __builtin_amdgcn_mfma_f32_16x16x32_bf16(ka, qfr[1], zero, 0, 0, 0);
    s[1][0] = __builtin_amdgcn_mfma_f32_16x16x32_bf16(kc, qfr[0], zero, 0, 0, 0);
    s[1][1] = __builtin_amdgcn_mfma_f32_16x16x32_bf16(kc, qfr[1], zero, 0, 0, 0);
    float p[2][2][4];
    #pragma unroll
    for (int kf = 0; kf < 2; kf++)
      #pragma unroll
      for (int qf = 0; qf < 2; qf++)
        #pragma unroll
        for (int r = 0; r < 4; r++) {
          float pe = __builtin_amdgcn_exp2f(s[kf][qf][r]);
          if (t == 28) {
            int kid = k0 + kf * 16 + quad * 4 + r;
            if (kid >= 900) pe = 0.f;
          }
          p[kf][qf][r] = pe;
          lsum[qf] += pe;
        }
    #pragma unroll
    for (int kf = 0; kf < 2; kf++)
      #pragma unroll
      for (int qf = 0; qf < 2; qf++)
        #pragma unroll
        for (int r = 0; r < 4; r += 2) {
          unsigned ua = __float_as_uint(p[kf][qf][r]) + 0x7fffu;
          unsigned ub = __float_as_uint(p[kf][qf][r + 1]) + 0x7fffu;
          unsigned pk = (ua >> 16) | (ub & 0xffff0000u);
          *(unsigned*)&P[wave][qf * 16 + l16][kf * 16 + quad * 4 + r] = pk;
        }
    #pragma unroll
    for (int qf = 0; qf < 2; qf++) {
      short8 pf = *(const short8*)&P[wave][qf * 16 + l16][quad * 8];
      acc[0][qf] = __builtin_amdgcn_mfma_f32_16x16x32_bf16(va, pf, acc[0][qf], 0, 0, 0);
      acc[1][qf] = __builtin_amdgcn_mfma_f32_16x16x32_bf16(vc, pf, acc[1][qf], 0, 0, 0);
    }
    ka = nka; kc = nkc; va = nva; vc = nvc;
  }
  #pragma unroll
  for (int qf = 0; qf < 2; qf++) {
    lsum[qf] += __shfl_xor(lsum[qf], 16);
    lsum[qf] += __shfl_xor(lsum[qf], 32);
  }
  #pragma unroll
  for (int df = 0; df < 2; df++)
    #pragma unroll
    for (int qf = 0; qf < 2; qf++) {
      int qg = q0 + qf * 16 + l16;
      if (qg < 900) {
        float inv = 1.f / lsum[qf];
        int d0 = df * 16 + quad * 4;
        short4v o4;
        o4.x = f2bf(acc[df][qf][0] * inv);
        o4.y = f2bf(acc[df][qf][1] * inv);
        o4.z = f2bf(acc[df][qf][2] * inv);
        o4.w = f2bf(acc[df][qf][3] * inv);
        *(short4v*)(att + (long)(qg * 8 + b) * 256 + h * 32 + d0) = o4;
      }
    }
}

// -------------------- residual + layernorm (optional bf16 / transposed bf16+pe out) ----
template<int BMODE>
__global__ __launch_bounds__(256) void resid_ln(
    const float* __restrict__ X, const float* __restrict__ R,
    const float* __restrict__ g, const float* __restrict__ be,
    float* __restrict__ out, short* __restrict__ obf,
    const float* __restrict__ qpe, short* __restrict__ obft) {
  int row = blockIdx.x;
  int d = threadIdx.x;
  long rrow;
  if (BMODE == 0) rrow = row;
  else { int b = row % B_BATCH; int n = row / B_BATCH; rrow = (long)b * NQ + n; }
  float x = X[(long)row * 256 + d] + R[rrow * 256 + d];
  float s1 = x, s2 = x * x;
  #pragma unroll
  for (int off = 32; off; off >>= 1) {
    s1 += __shfl_xor(s1, off);
    s2 += __shfl_xor(s2, off);
  }
  __shared__ float a1[4], a2[4];
  int w = d >> 6, lidx = d & 63;
  if (lidx == 0) { a1[w] = s1; a2[w] = s2; }
  __syncthreads();
  float S1 = a1[0] + a1[1] + a1[2] + a1[3];
  float S2 = a2[0] + a2[1] + a2[2] + a2[3];
  float mean = S1 * (1.f / 256.f);
  float var = S2 * (1.f / 256.f) - mean * mean;
  float y = (x - mean) * rsqrtf(var + 1e-5f) * g[d] + be[d];
  out[(long)row * 256 + d] = y;
  if (obf) obf[(long)row * 256 + d] = f2bf(y);
  if (obft) {   // row = n*B+b ; write bf16(y + qpe) at (b*NQ+n)
    int n = row >> 3, b = row & 7;
    obft[((long)b * NQ + n) * 256 + d] = f2bf(y + qpe[(long)row * 256 + d]);
  }
}

// -------------------- deformable-attention sampling (bf16 value, bf16 out) ------------
// offs/aw share a combined buffer with row stride 384.
__global__ __launch_bounds__(256) void deform_sample(
    const unsigned short* __restrict__ value, const float* __restrict__ offs,
    const float* __restrict__ aw, const float* __restrict__ qrp,
    short* __restrict__ samp) {
  int bq = blockIdx.x;  // b*NQ + q
  int b = bq / NQ, q = bq % NQ;
  int h = threadIdx.x >> 5, c = threadIdx.x & 31;
  __shared__ float Wl[8][16], Lx[8][16], Ly[8][16];
  if (c < 16) {
    float a = aw[(long)bq * 384 + h * 16 + c];
    float ox = offs[(long)bq * 384 + (h * 16 + c) * 2 + 0];
    float oy = offs[(long)bq * 384 + (h * 16 + c) * 2 + 1];
    const float* rp = qrp + ((long)q * B_BATCH + b) * 4;
    Lx[h][c] = rp[0] + ox * 0.25f * rp[2] * 0.5f;
    Ly[h][c] = rp[1] + oy * 0.25f * rp[3] * 0.5f;
    Wl[h][c] = a;
  }
  __syncthreads();
  if (threadIdx.x < 8) {
    int hh = threadIdx.x;
    float mx = -1e30f;
    for (int i = 0; i < 16; i++) mx = fmaxf(mx, Wl[hh][i]);
    float sm = 0.f;
    for (int i = 0; i < 16; i++) { float e = __expf(Wl[hh][i] - mx); Wl[hh][i] = e; sm += e; }
    float inv = 1.f / sm;
    for (int i = 0; i < 16; i++) Wl[hh][i] *= inv;
  }
  __syncthreads();
  const int lvlW[4] = {96, 48, 24, 12};
  const int lvlS[4] = {0, 9216, 11520, 12096};
  float acc = 0.f;
  const unsigned short* vb = value + (long)b * S_TOT * 256 + h * 32 + c;
  #pragma unroll
  for (int l = 0; l < 4; l++) {
    int ww = lvlW[l], hh2 = lvlW[l], st = lvlS[l];
    #pragma unroll
    for (int p = 0; p < 4; p++) {
      int lp = l * 4 + p;
      float wgt = Wl[h][lp];
      float x = Lx[h][lp] * ww - 0.5f;
      float y = Ly[h][lp] * hh2 - 0.5f;
      float x0f = floorf(x), y0f = floorf(y);
      float lx = x - x0f, ly = y - y0f;
      int x0 = (int)x0f, y0 = (int)y0f;
      #pragma unroll
      for (int cy = 0; cy < 2; cy++) {
        #pragma unroll
        for (int cx = 0; cx < 2; cx++) {
          int xi = x0 + cx, yi = y0 + cy;
          float cw = (cx ? lx : 1.f - lx) * (cy ? ly : 1.f - ly);
          bool valid = (xi >= 0) && (xi < ww) && (yi >= 0) && (yi < hh2);
          int xc = min(max(xi, 0), ww - 1);
          int yc = min(max(yi, 0), hh2 - 1);
          float vv = bf2f(vb[(long)(st + yc * ww + xc) * 256]);
          acc += (valid ? cw * wgt : 0.f) * vv;
        }
      }
    }
  }
  samp[(long)bq * 256 + h * 32 + c] = f2bf(acc);
}

// -------------------- host launch --------------------
extern "C" void kernel_launch(void* const* d_in, const int* in_sizes, int n_in,
                              void* d_out, int out_size, void* d_ws, size_t ws_size,
                              hipStream_t stream) {
  const float* queries = (const float*)d_in[0];
  const float* qpe     = (const float*)d_in[1];
  const float* qrp     = (const float*)d_in[2];
  const float* memory  = (const float*)d_in[3];
  const float* in_w    = (const float*)d_in[7];
  const float* in_b    = (const float*)d_in[8];
  const float* out_w   = (const float*)d_in[9];
  const float* out_b   = (const float*)d_in[10];
  const float* n1g = (const float*)d_in[11];
  const float* n1b = (const float*)d_in[12];
  const float* n2g = (const float*)d_in[13];
  const float* n2b = (const float*)d_in[14];
  const float* n3g = (const float*)d_in[15];
  const float* n3b = (const float*)d_in[16];
  const float* l1w = (const float*)d_in[17];
  const float* l1b = (const float*)d_in[18];
  const float* l2w = (const float*)d_in[19];
  const float* l2b = (const float*)d_in[20];
  const float* off_w = (const float*)d_in[21];
  const float* off_b = (const float*)d_in[22];
  const float* aw_w  = (const float*)d_in[23];
  const float* aw_b  = (const float*)d_in[24];
  const float* val_w = (const float*)d_in[25];
  const float* val_b = (const float*)d_in[26];
  const float* cout_w = (const float*)d_in[27];
  const float* cout_b = (const float*)d_in[28];

  float* ws = (float*)d_ws;
  const long E = (long)NROW * 256;        // 1,843,200
  float* slotA = ws + 0 * E;   // combined offs/aw [7200,384] (spans slotA+slotB)
  float* slotC = ws + 2 * E;   // sa -> ca -> ffn
  float* slotE = ws + 3 * E;   // q2
  float* slotF = ws + 4 * E;   // q3
  short* bfA = (short*)(ws + 5 * E);  // qk_bf -> samp_bf
  short* bfB = bfA + E;               // queries_bf -> qin_bf
  short* bfC = bfB + E;               // att_bf -> q3_bf
  short* wbf = bfC + E;               // weights bf16
  short* membt = wbf + 1540096;       // qk_h/vT -> hidden
  short* valbf = membt + 25067520;    // value bf16

  short* qk_h = membt;                          // [2][64][928][32]
  short* vT   = membt + 2L * 64 * KPAD * 32;    // [64][32][928]

  short* w_in   = wbf;                 // 196608 (Wq/Wk/Wv)
  short* w_out  = w_in + 196608;
  short* w_off  = w_out + 65536;       // [256,256]
  short* w_aw   = w_off + 65536;       // [128,256]  (contiguous after w_off -> [384,256])
  short* w_val  = w_aw + 32768;
  short* w_cout = w_val + 65536;
  short* w_l1   = w_cout + 65536;
  short* w_l2   = w_l1 + 524288;
  // combined off+aw bias
  // off_b (256) and aw_b (128) are separate arrays; deform reads them pre-added via GEMM
  // bias: we need a combined [384] fp32 bias buffer -> stash in ws after valbf region
  float* bias_offaw = (float*)(valbf + 25067520);  // 384 floats

  dim3 blk(256);
  dim3 g7200(NROW);
  const int E4 = (int)(E / 1024);      // 1800

  // 0. weights -> bf16 + combined bias copy
  WConvArgs wa;
  wa.src[0] = in_w;  wa.dst[0] = w_in;
  wa.src[1] = out_w; wa.dst[1] = w_out;
  wa.src[2] = off_w; wa.dst[2] = w_off;
  wa.src[3] = aw_w;  wa.dst[3] = w_aw;
  wa.src[4] = val_w; wa.dst[4] = w_val;
  wa.src[5] = cout_w;wa.dst[5] = w_cout;
  wa.src[6] = l1w;   wa.dst[6] = w_l1;
  wa.src[7] = l2w;   wa.dst[7] = w_l2;
  int cs[8] = {196608, 65536, 65536, 32768, 65536, 65536, 524288, 524288};
  int acc0 = 0;
  for (int i = 0; i < 8; i++) { acc0 += cs[i]; wa.end[i] = acc0; }
  wa.total = acc0;
  wconv_kernel<<<dim3((acc0 + 255) / 256), blk, 0, stream>>>(wa);
  hipMemcpyAsync(bias_offaw, off_b, 256 * sizeof(float), hipMemcpyDeviceToDevice, stream);
  hipMemcpyAsync(bias_offaw + 256, aw_b, 128 * sizeof(float), hipMemcpyDeviceToDevice, stream);

  // 1. qk_bf = bf16(queries + qpe); queries_bf = bf16(queries)
  addconv_kernel<<<dim3(E4), blk, 0, stream>>>(queries, qpe, bfA, bfB);
  // 2. in-proj: QK fused (N=512) -> head-split qk_h; V -> transposed vT
  gemm_bf16<false, 2, 128><<<dim3(4, 57), blk, 0, stream>>>(bfA, w_in, in_b, qk_h, NROW, 512, 256, 512);
  gemm_bf16<false, 3, 64><<<dim3(2, 113), blk, 0, stream>>>(bfB, w_in + 131072, in_b + 512, vT, NROW, 256, 256, 256);
  // 3. MFMA flash self-attention -> att_bf (bfC)
  attn_mfma<<<dim3(8, 64), blk, 0, stream>>>(qk_h, vT, bfC);
  // 4. out-proj -> sa (slotC)
  gemm_bf16<false, 0, 64><<<dim3(2, 113), blk, 0, stream>>>(bfC, w_out, out_b, slotC, NROW, 256, 256, 256);
  // 5. q2 = LN(queries + sa) [norm2] -> slotE; fused qin_bf = bf16((q2+qpe)^T) -> bfB
  resid_ln<0><<<g7200, blk, 0, stream>>>(queries, slotC, n2g, n2b, slotE, nullptr, qpe, bfB);
  // 6. combined offsets+aw projection (N=384, LDC=384) -> slotA
  gemm_bf16<false, 0, 64><<<dim3(3, 113), blk, 0, stream>>>(bfB, w_off, bias_offaw, slotA, NROW, 384, 256, 384);
  // 7. value projection direct from fp32 memory (fused transpose+conv) -> valbf
  gemm_val<<<dim3(2, 765), blk, 0, stream>>>(memory, w_val, val_b, valbf);
  // 8. deformable sampling -> samp_bf (bfA)
  deform_sample<<<g7200, blk, 0, stream>>>((const unsigned short*)valbf, slotA, slotA + 256, qrp, bfA);
  // 9. cross-attn output proj -> ca (slotC)
  gemm_bf16<false, 0, 64><<<dim3(2, 113), blk, 0, stream>>>(bfA, w_cout, cout_b, slotC, NROW, 256, 256, 256);
  // 10. q3 = LN(q2 + ca^T) [norm1] -> slotF (+ bf16 copy in bfC)
  resid_ln<1><<<g7200, blk, 0, stream>>>(slotE, slotC, n1g, n1b, slotF, bfC, nullptr, nullptr);
  // 11. FFN lin1 + relu -> hidden bf16 (membt reuse)
  gemm_bf16<true, 1, 128><<<dim3(16, 57), blk, 0, stream>>>(bfC, w_l1, l1b, membt, NROW, DFF, 256, DFF);
  // 12. FFN lin2 -> ffn (slotC)
  gemm_bf16<false, 0, 64><<<dim3(2, 113), blk, 0, stream>>>(membt, w_l2, l2b, slotC, NROW, 256, 2048, 256);
  // 13. out = LN(q3 + ffn) [norm3]
  resid_ln<0><<<g7200, blk, 0, stream>>>(slotF, slotC, n3g, n3b, (float*)d_out, nullptr, nullptr, nullptr);
}

// Round 8
// 431.512 us; speedup vs baseline: 5.5989x; 1.0318x over previous
//
#include <hip/hip_runtime.h>
#include <hip/hip_bf16.h>

// Problem constants (fixed by the reference)
#define D_DIM 256
#define H_HEADS 8
#define L_LVLS 4
#define P_PTS 4
#define DFF 2048
#define DH 32
#define NQ 900
#define B_BATCH 8
#define S_TOT 12240
#define NROW (NQ * B_BATCH)   // 7200
#define KPAD 928              // 900 keys padded to 29*32

typedef __attribute__((ext_vector_type(8))) short short8;
typedef __attribute__((ext_vector_type(4))) short short4v;
typedef __attribute__((ext_vector_type(4))) float f32x4;

// float -> bf16 round-to-nearest-even (inputs finite)
__device__ __forceinline__ short f2bf(float x) {
  union { float f; unsigned u; } v; v.f = x;
  unsigned r = v.u + 0x7fff + ((v.u >> 16) & 1);
  return (short)(r >> 16);
}
__device__ __forceinline__ float bf2f(unsigned short u) {
  union { unsigned u; float f; } v; v.u = ((unsigned)u) << 16; return v.f;
}

// ------------- fused preprocessing: weight conv (8 segs) + qk_bf/q_bf --------------
// blocks [0, NB_ADD): addconv on queries/qpe.  blocks [NB_ADD, ...): weight conv.
#define NB_ADD 1800
struct WConvArgs {
  const float* src[8];
  short* dst[8];
  int end[8];
  int total;
};
__global__ __launch_bounds__(256) void prep_kernel(
    WConvArgs a, const float* __restrict__ q, const float* __restrict__ p,
    short* __restrict__ qk_bf, short* __restrict__ q_bf) {
  if (blockIdx.x < NB_ADD) {
    int t = blockIdx.x * 256 + threadIdx.x;   // E/4 threads
    float4 x = ((const float4*)q)[t];
    float4 y = ((const float4*)p)[t];
    short4v s, ad;
    s.x = f2bf(x.x); s.y = f2bf(x.y); s.z = f2bf(x.z); s.w = f2bf(x.w);
    ad.x = f2bf(x.x + y.x); ad.y = f2bf(x.y + y.y);
    ad.z = f2bf(x.z + y.z); ad.w = f2bf(x.w + y.w);
    ((short4v*)q_bf)[t] = s;
    ((short4v*)qk_bf)[t] = ad;
  } else {
    int i = (blockIdx.x - NB_ADD) * 256 + threadIdx.x;
    if (i >= a.total) return;
    int seg = 0;
    while (seg < 7 && i >= a.end[seg]) seg++;
    int base = seg ? a.end[seg - 1] : 0;
    a.dst[seg][i - base] = f2bf(a.src[seg][i - base]);
  }
}

// ---------------- bf16 MFMA GEMM: C[M,N] = A[M,K] @ W[N,K]^T + bias ----------------
// Software-pipelined: next K-tile's global loads issue before the MFMAs, so the
// vmcnt wait (at the next LDS write) overlaps MFMA + ds_read of the current tile.
// TM = 128 (4 waves x 64x64) or 64 (4 waves x 32x64).  BN = 128.
// OMODE 0: fp32 flat (LDC).  1: bf16 flat (LDC).
// 2: QK head-split: m = nq*8+b, buf=n>>8 (0=q scaled by log2e/sqrt32, 1=k),
//    out[((buf*64 + b*8+h)*928 + nq)*32 + d].
// 3: V transposed: out[((b*8+h)*32 + d)*928 + nq].
template<bool RELU, int OMODE, int TM>
__global__ __launch_bounds__(256) void gemm_bf16(
    const short* __restrict__ A, const short* __restrict__ W,
    const float* __restrict__ bias, void* __restrict__ Cv,
    int M, int N, int K, int LDC) {
  constexpr int MI = (TM == 128) ? 4 : 2;
  __shared__ short As[TM * 40];
  __shared__ short Bs[128 * 40];
  int tid = threadIdx.x;
  int wave = tid >> 6, lane = tid & 63;
  int wm = wave >> 1, wn = wave & 1;
  int quad = lane >> 4, l16 = lane & 15;
  int m0 = blockIdx.y * TM, n0 = blockIdx.x * 128;
  int srowB = tid >> 1, shalfB = tid & 1;
  const short* bsrc = W + (long)(n0 + srowB) * K + shalfB * 16;
  short* bdst = &Bs[srowB * 40 + shalfB * 16];
  const short* asrc; short* adst; bool avalid;
  if (TM == 128) {
    int srow = tid >> 1, shalf = tid & 1;
    int am = m0 + srow;
    avalid = am < M;
    asrc = A + (long)(avalid ? am : 0) * K + shalf * 16;
    adst = &As[srow * 40 + shalf * 16];
  } else {
    int srow = tid >> 2, spart = tid & 3;
    int am = m0 + srow;
    avalid = am < M;
    asrc = A + (long)(avalid ? am : 0) * K + spart * 8;
    adst = &As[srow * 40 + spart * 8];
  }
  f32x4 acc[MI][4] = {};
  // preload tile 0
  short8 ta0 = {}, ta1 = {}, tb0, tb1;
  if (avalid) {
    ta0 = *(const short8*)(asrc);
    if (TM == 128) ta1 = *(const short8*)(asrc + 8);
  }
  tb0 = *(const short8*)(bsrc);
  tb1 = *(const short8*)(bsrc + 8);
  for (int k0 = 0; k0 < K; k0 += 32) {
    __syncthreads();
    *(short8*)adst = ta0;
    if (TM == 128) *(short8*)(adst + 8) = ta1;
    *(short8*)bdst = tb0;
    *(short8*)(bdst + 8) = tb1;
    __syncthreads();
    int kn = k0 + 32;
    if (kn < K) {
      if (avalid) {
        ta0 = *(const short8*)(asrc + kn);
        if (TM == 128) ta1 = *(const short8*)(asrc + kn + 8);
      }
      tb0 = *(const short8*)(bsrc + kn);
      tb1 = *(const short8*)(bsrc + kn + 8);
    }
    short8 af[MI], bf[4];
    #pragma unroll
    for (int i = 0; i < MI; i++)
      af[i] = *(const short8*)&As[(wm * (TM / 2) + i * 16 + l16) * 40 + quad * 8];
    #pragma unroll
    for (int j = 0; j < 4; j++)
      bf[j] = *(const short8*)&Bs[(wn * 64 + j * 16 + l16) * 40 + quad * 8];
    #pragma unroll
    for (int i = 0; i < MI; i++)
      #pragma unroll
      for (int j = 0; j < 4; j++)
        acc[i][j] = __builtin_amdgcn_mfma_f32_16x16x32_bf16(af[i], bf[j], acc[i][j], 0, 0, 0);
  }
  #pragma unroll
  for (int i = 0; i < MI; i++) {
    int mbase = m0 + wm * (TM / 2) + i * 16 + quad * 4;
    #pragma unroll
    for (int r = 0; r < 4; r++) {
      int m = mbase + r;
      if (m < M) {
        #pragma unroll
        for (int j = 0; j < 4; j++) {
          int n = n0 + wn * 64 + j * 16 + l16;
          float v = acc[i][j][r] + bias[n];
          if (RELU) v = fmaxf(v, 0.f);
          if (OMODE == 0) {
            ((float*)Cv)[(long)m * LDC + n] = v;
          } else if (OMODE == 1) {
            ((short*)Cv)[(long)m * LDC + n] = f2bf(v);
          } else if (OMODE == 2) {
            int nq = m >> 3, bb = m & 7;
            int buf = n >> 8, hh = (n >> 5) & 7, dd = n & 31;
            if (buf == 0) v *= 0.25503483f;   // log2(e)/sqrt(32)
            ((short*)Cv)[((long)(buf * 64 + bb * 8 + hh) * KPAD + nq) * 32 + dd] = f2bf(v);
          } else {
            int nq = m >> 3, bb = m & 7;
            int hh = n >> 5, dd = n & 31;
            ((short*)Cv)[((long)(bb * 8 + hh) * 32 + dd) * KPAD + nq] = f2bf(v);
          }
        }
      }
    }
  }
}

// ---------------- value GEMM: fp32 A in (S,B,D), fused bf16 conv, bf16 out ------------
// Software-pipelined like gemm_bf16.  m = b*S + s reads A row s*B + b.
__global__ __launch_bounds__(256) void gemm_val(
    const float* __restrict__ A, const short* __restrict__ W,
    const float* __restrict__ bias, short* __restrict__ C) {
  __shared__ short As[128 * 40];
  __shared__ short Bs[128 * 40];
  int tid = threadIdx.x;
  int wave = tid >> 6, lane = tid & 63;
  int wm = wave >> 1, wn = wave & 1;
  int quad = lane >> 4, l16 = lane & 15;
  int m0 = blockIdx.y * 128, n0 = blockIdx.x * 128;
  int srow = tid >> 1, shalf = tid & 1;
  int am = m0 + srow;
  int b = am / S_TOT, s = am - b * S_TOT;
  const float* asrc = A + ((long)s * B_BATCH + b) * 256 + shalf * 16;
  const short* bsrc = W + (long)(n0 + srow) * 256 + shalf * 16;
  short* adst = &As[srow * 40 + shalf * 16];
  short* bdst = &Bs[srow * 40 + shalf * 16];
  f32x4 acc[4][4] = {};
  // preload tile 0
  float4 f0 = ((const float4*)asrc)[0];
  float4 f1 = ((const float4*)asrc)[1];
  float4 f2 = ((const float4*)asrc)[2];
  float4 f3 = ((const float4*)asrc)[3];
  short8 tb0 = *(const short8*)(bsrc);
  short8 tb1 = *(const short8*)(bsrc + 8);
  for (int k0 = 0; k0 < 256; k0 += 32) {
    short8 ta0, ta1;
    ta0[0]=f2bf(f0.x); ta0[1]=f2bf(f0.y); ta0[2]=f2bf(f0.z); ta0[3]=f2bf(f0.w);
    ta0[4]=f2bf(f1.x); ta0[5]=f2bf(f1.y); ta0[6]=f2bf(f1.z); ta0[7]=f2bf(f1.w);
    ta1[0]=f2bf(f2.x); ta1[1]=f2bf(f2.y); ta1[2]=f2bf(f2.z); ta1[3]=f2bf(f2.w);
    ta1[4]=f2bf(f3.x); ta1[5]=f2bf(f3.y); ta1[6]=f2bf(f3.z); ta1[7]=f2bf(f3.w);
    __syncthreads();
    *(short8*)adst = ta0;
    *(short8*)(adst + 8) = ta1;
    *(short8*)bdst = tb0;
    *(short8*)(bdst + 8) = tb1;
    __syncthreads();
    int kn = k0 + 32;
    if (kn < 256) {
      f0 = ((const float4*)(asrc + kn))[0];
      f1 = ((const float4*)(asrc + kn))[1];
      f2 = ((const float4*)(asrc + kn))[2];
      f3 = ((const float4*)(asrc + kn))[3];
      tb0 = *(const short8*)(bsrc + kn);
      tb1 = *(const short8*)(bsrc + kn + 8);
    }
    short8 af[4], bf[4];
    #pragma unroll
    for (int i = 0; i < 4; i++) {
      af[i] = *(const short8*)&As[(wm * 64 + i * 16 + l16) * 40 + quad * 8];
      bf[i] = *(const short8*)&Bs[(wn * 64 + i * 16 + l16) * 40 + quad * 8];
    }
    #pragma unroll
    for (int i = 0; i < 4; i++)
      #pragma unroll
      for (int j = 0; j < 4; j++)
        acc[i][j] = __builtin_amdgcn_mfma_f32_16x16x32_bf16(af[i], bf[j], acc[i][j], 0, 0, 0);
  }
  #pragma unroll
  for (int i = 0; i < 4; i++) {
    int mbase = m0 + wm * 64 + i * 16 + quad * 4;
    #pragma unroll
    for (int r = 0; r < 4; r++) {
      int m = mbase + r;
      #pragma unroll
      for (int j = 0; j < 4; j++) {
        int n = n0 + wn * 64 + j * 16 + l16;
        C[(long)m * 256 + n] = f2bf(acc[i][j][r] + bias[n]);
      }
    }
  }
}

// -------------------- MFMA flash self-attention --------------------
__global__ __launch_bounds__(256) void attn_mfma(
    const short* __restrict__ qk_h, const short* __restrict__ vT,
    short* __restrict__ att) {
  int bh = blockIdx.y; int b = bh >> 3, h = bh & 7;
  int tid = threadIdx.x; int wave = tid >> 6, lane = tid & 63;
  int quad = lane >> 4, l16 = lane & 15;
  int q0 = blockIdx.x * 128 + wave * 32;
  const short* qb = qk_h + (long)bh * KPAD * 32;
  const short* kb = qk_h + (long)(64 + bh) * KPAD * 32;
  const short* vb = vT + (long)bh * 32 * KPAD;
  __shared__ short P[4][32][40];
  short8 qfr[2];
  #pragma unroll
  for (int i = 0; i < 2; i++) {
    int qrow = q0 + i * 16 + l16; if (qrow > 927) qrow = 927;
    qfr[i] = *(const short8*)(qb + (long)qrow * 32 + quad * 8);
  }
  f32x4 acc[2][2] = {};
  float lsum[2] = {0.f, 0.f};
  const f32x4 zero = {0.f, 0.f, 0.f, 0.f};
  short8 ka = *(const short8*)(kb + (long)l16 * 32 + quad * 8);
  short8 kc = *(const short8*)(kb + (long)(16 + l16) * 32 + quad * 8);
  short8 va = *(const short8*)(vb + (long)l16 * KPAD + quad * 8);
  short8 vc = *(const short8*)(vb + (long)(16 + l16) * KPAD + quad * 8);
  for (int t = 0; t < 29; t++) {
    int k0 = t * 32;
    int kn = (t < 28) ? k0 + 32 : k0;
    short8 nka = *(const short8*)(kb + (long)(kn + l16) * 32 + quad * 8);
    short8 nkc = *(const short8*)(kb + (long)(kn + 16 + l16) * 32 + quad * 8);
    short8 nva = *(const short8*)(vb + (long)l16 * KPAD + kn + quad * 8);
    short8 nvc = *(const short8*)(vb + (long)(16 + l16) * KPAD + kn + quad * 8);
    f32x4 s[2][2];
    s[0][0] = __builtin_amdgcn_mfma_f32_16x16x32_bf16(ka, qfr[0], zero, 0, 0, 0);
    s[0][1] = __builtin_amdgcn_mfma_f32_16x16x32_bf16(ka, qfr[1], zero, 0, 0, 0);
    s[1][0] = __builtin_amdgcn_mfma_f32_16x16x32_bf16(kc, qfr[0], zero, 0, 0, 0);
    s[1][1] = __builtin_amdgcn_mfma_f32_16x16x32_bf16(kc, qfr[1], zero, 0, 0, 0);
    float p[2][2][4];
    #pragma unroll
    for (int kf = 0; kf < 2; kf++)
      #pragma unroll
      for (int qf = 0; qf < 2; qf++)
        #pragma unroll
        for (int r = 0; r < 4; r++) {
          float pe = __builtin_amdgcn_exp2f(s[kf][qf][r]);
          if (t == 28) {
            int kid = k0 + kf * 16 + quad * 4 + r;
            if (kid >= 900) pe = 0.f;
          }
          p[kf][qf][r] = pe;
          lsum[qf] += pe;
        }
    #pragma unroll
    for (int kf = 0; kf < 2; kf++)
      #pragma unroll
      for (int qf = 0; qf < 2; qf++)
        #pragma unroll
        for (int r = 0; r < 4; r += 2) {
          unsigned ua = __float_as_uint(p[kf][qf][r]) + 0x7fffu;
          unsigned ub = __float_as_uint(p[kf][qf][r + 1]) + 0x7fffu;
          unsigned pk = (ua >> 16) | (ub & 0xffff0000u);
          *(unsigned*)&P[wave][qf * 16 + l16][kf * 16 + quad * 4 + r] = pk;
        }
    #pragma unroll
    for (int qf = 0; qf < 2; qf++) {
      short8 pf = *(const short8*)&P[wave][qf * 16 + l16][quad * 8];
      acc[0][qf] = __builtin_amdgcn_mfma_f32_16x16x32_bf16(va, pf, acc[0][qf], 0, 0, 0);
      acc[1][qf] = __builtin_amdgcn_mfma_f32_16x16x32_bf16(vc, pf, acc[1][qf], 0, 0, 0);
    }
    ka = nka; kc = nkc; va = nva; vc = nvc;
  }
  #pragma unroll
  for (int qf = 0; qf < 2; qf++) {
    lsum[qf] += __shfl_xor(lsum[qf], 16);
    lsum[qf] += __shfl_xor(lsum[qf], 32);
  }
  #pragma unroll
  for (int df = 0; df < 2; df++)
    #pragma unroll
    for (int qf = 0; qf < 2; qf++) {
      int qg = q0 + qf * 16 + l16;
      if (qg < 900) {
        float inv = 1.f / lsum[qf];
        int d0 = df * 16 + quad * 4;
        short4v o4;
        o4.x = f2bf(acc[df][qf][0] * inv);
        o4.y = f2bf(acc[df][qf][1] * inv);
        o4.z = f2bf(acc[df][qf][2] * inv);
        o4.w = f2bf(acc[df][qf][3] * inv);
        *(short4v*)(att + (long)(qg * 8 + b) * 256 + h * 32 + d0) = o4;
      }
    }
}

// -------------------- residual + layernorm (optional bf16 / transposed bf16+pe out) ----
template<int BMODE>
__global__ __launch_bounds__(256) void resid_ln(
    const float* __restrict__ X, const float* __restrict__ R,
    const float* __restrict__ g, const float* __restrict__ be,
    float* __restrict__ out, short* __restrict__ obf,
    const float* __restrict__ qpe, short* __restrict__ obft) {
  int row = blockIdx.x;
  int d = threadIdx.x;
  long rrow;
  if (BMODE == 0) rrow = row;
  else { int b = row % B_BATCH; int n = row / B_BATCH; rrow = (long)b * NQ + n; }
  float x = X[(long)row * 256 + d] + R[rrow * 256 + d];
  float s1 = x, s2 = x * x;
  #pragma unroll
  for (int off = 32; off; off >>= 1) {
    s1 += __shfl_xor(s1, off);
    s2 += __shfl_xor(s2, off);
  }
  __shared__ float a1[4], a2[4];
  int w = d >> 6, lidx = d & 63;
  if (lidx == 0) { a1[w] = s1; a2[w] = s2; }
  __syncthreads();
  float S1 = a1[0] + a1[1] + a1[2] + a1[3];
  float S2 = a2[0] + a2[1] + a2[2] + a2[3];
  float mean = S1 * (1.f / 256.f);
  float var = S2 * (1.f / 256.f) - mean * mean;
  float y = (x - mean) * rsqrtf(var + 1e-5f) * g[d] + be[d];
  out[(long)row * 256 + d] = y;
  if (obf) obf[(long)row * 256 + d] = f2bf(y);
  if (obft) {   // row = n*B+b ; write bf16(y + qpe) at (b*NQ+n)
    int n = row >> 3, b = row & 7;
    obft[((long)b * NQ + n) * 256 + d] = f2bf(y + qpe[(long)row * 256 + d]);
  }
}

// -------------------- deformable-attention sampling (bf16 value, bf16 out) ------------
// offs/aw share a combined buffer with row stride 384.
__global__ __launch_bounds__(256) void deform_sample(
    const unsigned short* __restrict__ value, const float* __restrict__ offs,
    const float* __restrict__ aw, const float* __restrict__ qrp,
    short* __restrict__ samp) {
  int bq = blockIdx.x;  // b*NQ + q
  int b = bq / NQ, q = bq % NQ;
  int h = threadIdx.x >> 5, c = threadIdx.x & 31;
  __shared__ float Wl[8][16], Lx[8][16], Ly[8][16];
  if (c < 16) {
    float a = aw[(long)bq * 384 + h * 16 + c];
    float ox = offs[(long)bq * 384 + (h * 16 + c) * 2 + 0];
    float oy = offs[(long)bq * 384 + (h * 16 + c) * 2 + 1];
    const float* rp = qrp + ((long)q * B_BATCH + b) * 4;
    Lx[h][c] = rp[0] + ox * 0.25f * rp[2] * 0.5f;
    Ly[h][c] = rp[1] + oy * 0.25f * rp[3] * 0.5f;
    Wl[h][c] = a;
  }
  __syncthreads();
  if (threadIdx.x < 8) {
    int hh = threadIdx.x;
    float mx = -1e30f;
    for (int i = 0; i < 16; i++) mx = fmaxf(mx, Wl[hh][i]);
    float sm = 0.f;
    for (int i = 0; i < 16; i++) { float e = __expf(Wl[hh][i] - mx); Wl[hh][i] = e; sm += e; }
    float inv = 1.f / sm;
    for (int i = 0; i < 16; i++) Wl[hh][i] *= inv;
  }
  __syncthreads();
  const int lvlW[4] = {96, 48, 24, 12};
  const int lvlS[4] = {0, 9216, 11520, 12096};
  float acc = 0.f;
  const unsigned short* vb = value + (long)b * S_TOT * 256 + h * 32 + c;
  #pragma unroll
  for (int l = 0; l < 4; l++) {
    int ww = lvlW[l], hh2 = lvlW[l], st = lvlS[l];
    #pragma unroll
    for (int p = 0; p < 4; p++) {
      int lp = l * 4 + p;
      float wgt = Wl[h][lp];
      float x = Lx[h][lp] * ww - 0.5f;
      float y = Ly[h][lp] * hh2 - 0.5f;
      float x0f = floorf(x), y0f = floorf(y);
      float lx = x - x0f, ly = y - y0f;
      int x0 = (int)x0f, y0 = (int)y0f;
      #pragma unroll
      for (int cy = 0; cy < 2; cy++) {
        #pragma unroll
        for (int cx = 0; cx < 2; cx++) {
          int xi = x0 + cx, yi = y0 + cy;
          float cw = (cx ? lx : 1.f - lx) * (cy ? ly : 1.f - ly);
          bool valid = (xi >= 0) && (xi < ww) && (yi >= 0) && (yi < hh2);
          int xc = min(max(xi, 0), ww - 1);
          int yc = min(max(yi, 0), hh2 - 1);
          float vv = bf2f(vb[(long)(st + yc * ww + xc) * 256]);
          acc += (valid ? cw * wgt : 0.f) * vv;
        }
      }
    }
  }
  samp[(long)bq * 256 + h * 32 + c] = f2bf(acc);
}

// -------------------- host launch --------------------
extern "C" void kernel_launch(void* const* d_in, const int* in_sizes, int n_in,
                              void* d_out, int out_size, void* d_ws, size_t ws_size,
                              hipStream_t stream) {
  const float* queries = (const float*)d_in[0];
  const float* qpe     = (const float*)d_in[1];
  const float* qrp     = (const float*)d_in[2];
  const float* memory  = (const float*)d_in[3];
  const float* in_w    = (const float*)d_in[7];
  const float* in_b    = (const float*)d_in[8];
  const float* out_w   = (const float*)d_in[9];
  const float* out_b   = (const float*)d_in[10];
  const float* n1g = (const float*)d_in[11];
  const float* n1b = (const float*)d_in[12];
  const float* n2g = (const float*)d_in[13];
  const float* n2b = (const float*)d_in[14];
  const float* n3g = (const float*)d_in[15];
  const float* n3b = (const float*)d_in[16];
  const float* l1w = (const float*)d_in[17];
  const float* l1b = (const float*)d_in[18];
  const float* l2w = (const float*)d_in[19];
  const float* l2b = (const float*)d_in[20];
  const float* off_w = (const float*)d_in[21];
  const float* off_b = (const float*)d_in[22];
  const float* aw_w  = (const float*)d_in[23];
  const float* aw_b  = (const float*)d_in[24];
  const float* val_w = (const float*)d_in[25];
  const float* val_b = (const float*)d_in[26];
  const float* cout_w = (const float*)d_in[27];
  const float* cout_b = (const float*)d_in[28];

  float* ws = (float*)d_ws;
  const long E = (long)NROW * 256;        // 1,843,200
  float* slotA = ws + 0 * E;   // combined offs/aw [7200,384] (spans 2 slots)
  float* slotC = ws + 2 * E;   // sa -> ca -> ffn
  float* slotE = ws + 3 * E;   // q2
  float* slotF = ws + 4 * E;   // q3
  short* bfA = (short*)(ws + 5 * E);  // qk_bf -> samp_bf
  short* bfB = bfA + E;               // queries_bf -> qin_bf
  short* bfC = bfB + E;               // att_bf -> q3_bf
  short* wbf = bfC + E;               // weights bf16
  short* membt = wbf + 1540096;       // qk_h/vT -> hidden
  short* valbf = membt + 25067520;    // value bf16

  short* qk_h = membt;                          // [2][64][928][32]
  short* vT   = membt + 2L * 64 * KPAD * 32;    // [64][32][928]

  short* w_in   = wbf;                 // 196608 (Wq/Wk/Wv)
  short* w_out  = w_in + 196608;
  short* w_off  = w_out + 65536;       // [256,256]
  short* w_aw   = w_off + 65536;       // [128,256] (contiguous -> [384,256])
  short* w_val  = w_aw + 32768;
  short* w_cout = w_val + 65536;
  short* w_l1   = w_cout + 65536;
  short* w_l2   = w_l1 + 524288;
  float* bias_offaw = (float*)(valbf + 25067520);  // 384 floats

  dim3 blk(256);
  dim3 g7200(NROW);

  // 0. fused prep: weights -> bf16 + qk_bf/q_bf
  WConvArgs wa;
  wa.src[0] = in_w;  wa.dst[0] = w_in;
  wa.src[1] = out_w; wa.dst[1] = w_out;
  wa.src[2] = off_w; wa.dst[2] = w_off;
  wa.src[3] = aw_w;  wa.dst[3] = w_aw;
  wa.src[4] = val_w; wa.dst[4] = w_val;
  wa.src[5] = cout_w;wa.dst[5] = w_cout;
  wa.src[6] = l1w;   wa.dst[6] = w_l1;
  wa.src[7] = l2w;   wa.dst[7] = w_l2;
  int cs[8] = {196608, 65536, 65536, 32768, 65536, 65536, 524288, 524288};
  int acc0 = 0;
  for (int i = 0; i < 8; i++) { acc0 += cs[i]; wa.end[i] = acc0; }
  wa.total = acc0;
  int nbw = (acc0 + 255) / 256;
  prep_kernel<<<dim3(NB_ADD + nbw), blk, 0, stream>>>(wa, queries, qpe, bfA, bfB);
  hipMemcpyAsync(bias_offaw, off_b, 256 * sizeof(float), hipMemcpyDeviceToDevice, stream);
  hipMemcpyAsync(bias_offaw + 256, aw_b, 128 * sizeof(float), hipMemcpyDeviceToDevice, stream);

  // 1. in-proj: QK fused (N=512) -> head-split qk_h; V -> transposed vT
  gemm_bf16<false, 2, 128><<<dim3(4, 57), blk, 0, stream>>>(bfA, w_in, in_b, qk_h, NROW, 512, 256, 512);
  gemm_bf16<false, 3, 64><<<dim3(2, 113), blk, 0, stream>>>(bfB, w_in + 131072, in_b + 512, vT, NROW, 256, 256, 256);
  // 2. MFMA flash self-attention -> att_bf (bfC)
  attn_mfma<<<dim3(8, 64), blk, 0, stream>>>(qk_h, vT, bfC);
  // 3. out-proj -> sa (slotC)
  gemm_bf16<false, 0, 64><<<dim3(2, 113), blk, 0, stream>>>(bfC, w_out, out_b, slotC, NROW, 256, 256, 256);
  // 4. q2 = LN(queries + sa) [norm2] -> slotE; fused qin_bf -> bfB
  resid_ln<0><<<g7200, blk, 0, stream>>>(queries, slotC, n2g, n2b, slotE, nullptr, qpe, bfB);
  // 5. combined offsets+aw projection (N=384, LDC=384) -> slotA
  gemm_bf16<false, 0, 64><<<dim3(3, 113), blk, 0, stream>>>(bfB, w_off, bias_offaw, slotA, NROW, 384, 256, 384);
  // 6. value projection direct from fp32 memory -> valbf
  gemm_val<<<dim3(2, 765), blk, 0, stream>>>(memory, w_val, val_b, valbf);
  // 7. deformable sampling -> samp_bf (bfA)
  deform_sample<<<g7200, blk, 0, stream>>>((const unsigned short*)valbf, slotA, slotA + 256, qrp, bfA);
  // 8. cross-attn output proj -> ca (slotC)
  gemm_bf16<false, 0, 64><<<dim3(2, 113), blk, 0, stream>>>(bfA, w_cout, cout_b, slotC, NROW, 256, 256, 256);
  // 9. q3 = LN(q2 + ca^T) [norm1] -> slotF (+ bf16 copy in bfC)
  resid_ln<1><<<g7200, blk, 0, stream>>>(slotE, slotC, n1g, n1b, slotF, bfC, nullptr, nullptr);
  // 10. FFN lin1 + relu -> hidden bf16 (membt reuse)
  gemm_bf16<true, 1, 128><<<dim3(16, 57), blk, 0, stream>>>(bfC, w_l1, l1b, membt, NROW, DFF, 256, DFF);
  // 11. FFN lin2 -> ffn (slotC)
  gemm_bf16<false, 0, 64><<<dim3(2, 113), blk, 0, stream>>>(membt, w_l2, l2b, slotC, NROW, 256, 2048, 256);
  // 12. out = LN(q3 + ffn) [norm3]
  resid_ln<0><<<g7200, blk, 0, stream>>>(slotF, slotC, n3g, n3b, (float*)d_out, nullptr, nullptr, nullptr);
}